// Round 18
// baseline (524.278 us; speedup 1.0000x reference)
//
#include <hip/hip_runtime.h>
#include <hip/hip_fp16.h>
#include <cstdint>
#include <cstddef>

// RWKV_Tmix_headmixer — round 18: R15 GEMM inner loop (dist-1, known-good)
// + 32x32 GEMM tiles: 2x waves for the latency-bound GEMM trio
// (final gemm was at 1 wave/SIMD). Attention kernels byte-identical to R15.
// B=1, T=2048, C=1024, H=16, K=64.

#define C_DIM 1024
#define HEADS 16
#define TQ 16
#define SCH 256
#define PADS 40
#define EPS 36
#define FIXED_M 40.0f

typedef unsigned short ushort_t;
typedef __attribute__((ext_vector_type(8))) short bf16x8;
typedef __attribute__((ext_vector_type(4))) float f32x4;

#define MFMA16(a, b, c) __builtin_amdgcn_mfma_f32_16x16x32_bf16(a, b, c, 0, 0, 0)

__device__ __forceinline__ unsigned int f2bf_u(float f) {
  unsigned int u = __float_as_uint(f);
  return (u + 0x7fffu + ((u >> 16) & 1u)) >> 16;   // RNE
}
__device__ __forceinline__ float bf2f(ushort_t u) {
  return __uint_as_float(((unsigned int)u) << 16);
}
__device__ __forceinline__ void pack4(ushort_t* dst, float x0, float x1,
                                      float x2, float x3) {
  uint2 v;
  v.x = f2bf_u(x0) | (f2bf_u(x1) << 16);
  v.y = f2bf_u(x2) | (f2bf_u(x3) << 16);
  *(uint2*)dst = v;
}
// packed y3 tile-slot offset: ntiles(tbi) = ceil((t0+16)/32), t0=(127-tbi)*16
__device__ __forceinline__ int y3_off(int tbi) {
  const int m = tbi >> 1;
  const int S = m*(m-1) + ((tbi & 1) ? m : 0);
  return 64*tbi - S;
}

// ---------------- K1: prep_all = prep + wlora_prep + wprep(x4) -------------
__global__ __launch_bounds__(256) void prep_all(
    const float* __restrict__ x, const float* __restrict__ shift,
    const float* __restrict__ maa_x,
    float* __restrict__ dxprev, ushort_t* __restrict__ zbf,
    ushort_t* __restrict__ xbf,
    const float* __restrict__ w1, const float* __restrict__ hw1,
    ushort_t* __restrict__ wlt,
    const float* __restrict__ w_r, const float* __restrict__ w_k,
    const float* __restrict__ w_v, const float* __restrict__ w_o,
    ushort_t* __restrict__ wtr, ushort_t* __restrict__ wtk,
    ushort_t* __restrict__ wtv, ushort_t* __restrict__ wto, int T)
{
  __shared__ float tile[32][33];
  const int bid = blockIdx.x;
  const int tid = threadIdx.x;
  if (bid < T) {                       // ---- prep ----
    const int t = bid;
    const int c = tid * 4;
    const size_t base = (size_t)t * C_DIM + c;
    const float4 xc = *(const float4*)&x[base];
    const float4 xp = (t == 0) ? *(const float4*)&shift[c]
                               : *(const float4*)&x[base - C_DIM];
    const float4 mx = *(const float4*)&maa_x[c];
    float4 d;
    d.x = xp.x - xc.x; d.y = xp.y - xc.y; d.z = xp.z - xc.z; d.w = xp.w - xc.w;
    *(float4*)&dxprev[base] = d;
    pack4(&zbf[base], xc.x + d.x*mx.x, xc.y + d.y*mx.y,
          xc.z + d.z*mx.z, xc.w + d.w*mx.w);
    pack4(&xbf[base], xc.x, xc.y, xc.z, xc.w);
  } else if (bid < T + 224) {          // ---- wlora_prep ----
    const int b = bid - T;
    const int k0 = (b & 31) * 32, j0 = (b >> 5) * 32;
    const int r = tid >> 3, c4 = (tid & 7) * 4;
    const float* W = (j0 < 96) ? w1 : hw1;
    const int stride = (j0 < 96) ? 96 : 128;
    const int jo = (j0 < 96) ? j0 : j0 - 96;
    const float4 v = *(const float4*)&W[(size_t)(k0+r)*stride + jo + c4];
    tile[r][c4+0] = v.x; tile[r][c4+1] = v.y;
    tile[r][c4+2] = v.z; tile[r][c4+3] = v.w;
    __syncthreads();
    pack4(&wlt[(size_t)(j0+r)*C_DIM + k0 + c4],
          tile[c4+0][r], tile[c4+1][r], tile[c4+2][r], tile[c4+3][r]);
  } else {                             // ---- wprep x4 ----
    const int b = bid - T - 224;
    const int z = b >> 10, rr = b & 1023;
    const int k0 = (rr & 31) * 32, n0 = (rr >> 5) * 32;
    const float* W; ushort_t* O;
    if (z == 0)      { W = w_r; O = wtr; }
    else if (z == 1) { W = w_k; O = wtk; }
    else if (z == 2) { W = w_v; O = wtv; }
    else             { W = w_o; O = wto; }
    const int r = tid >> 3, c4 = (tid & 7) * 4;
    const float4 v = *(const float4*)&W[(size_t)(k0+r)*C_DIM + n0 + c4];
    tile[r][c4+0] = v.x; tile[r][c4+1] = v.y;
    tile[r][c4+2] = v.z; tile[r][c4+3] = v.w;
    __syncthreads();
    pack4(&O[(size_t)(n0+r)*C_DIM + k0 + c4],
          tile[c4+0][r], tile[c4+1][r], tile[c4+2][r], tile[c4+3][r]);
  }
}

// ---------------- K2: lora GEMM (R15 dist-1) ----------------
__global__ __launch_bounds__(64) void lora_gemm(
    const ushort_t* __restrict__ zbf, const ushort_t* __restrict__ xbf,
    const ushort_t* __restrict__ wlt, float* __restrict__ xxx,
    float* __restrict__ ha)
{
  const int nt = blockIdx.y;
  const int bm = blockIdx.x * 32;
  const ushort_t* A = (nt < 3) ? zbf : xbf;
  const int wrow = nt * 32;
  const int lane = threadIdx.x;
  const int l15 = lane & 15, g = lane >> 4;
  f32x4 acc[2][2];
  #pragma unroll
  for (int i = 0; i < 2; i++)
    #pragma unroll
    for (int j = 0; j < 2; j++) acc[i][j] = (f32x4){0.f,0.f,0.f,0.f};
  bf16x8 a0[2], b0[2], a1[2], b1[2];
  #define LLA(aa, bb, kk) { \
    _Pragma("unroll") \
    for (int i = 0; i < 2; i++) { \
      aa[i] = *(const bf16x8*)&A[(size_t)(bm + i*16 + l15)*C_DIM + (kk) + g*8]; \
      bb[i] = *(const bf16x8*)&wlt[(size_t)(wrow + i*16 + l15)*C_DIM + (kk) + g*8]; \
    } }
  LLA(a0, b0, 0);
  for (int k0 = 0; k0 < C_DIM; k0 += 64) {
    LLA(a1, b1, k0+32);
    #pragma unroll
    for (int i = 0; i < 2; i++)
      #pragma unroll
      for (int j = 0; j < 2; j++) acc[i][j] = MFMA16(a0[i], b0[j], acc[i][j]);
    if (k0 + 64 < C_DIM) LLA(a0, b0, k0+64);
    #pragma unroll
    for (int i = 0; i < 2; i++)
      #pragma unroll
      for (int j = 0; j < 2; j++) acc[i][j] = MFMA16(a1[i], b1[j], acc[i][j]);
  }
  #undef LLA
  #pragma unroll
  for (int i = 0; i < 2; i++)
    #pragma unroll
    for (int j = 0; j < 2; j++)
      #pragma unroll
      for (int r = 0; r < 4; r++) {
        const int t = bm + i*16 + g*4 + r;
        const int col = wrow + j*16 + l15;
        const float val = tanhf(acc[i][j][r]);
        if (nt < 3) xxx[(size_t)t*96 + col] = val;
        else        ha[(size_t)t*128 + col - 96] = val;
      }
}

// ---------------- K3: mix + hm ----------------
__global__ __launch_bounds__(256) void mix_hm(
    const float* __restrict__ x, const float* __restrict__ dxp,
    const float* __restrict__ xxx, const float* __restrict__ ha,
    const float* __restrict__ maa_r, const float* __restrict__ maa_k,
    const float* __restrict__ maa_v, const float* __restrict__ w2,
    const float* __restrict__ hw2,
    ushort_t* __restrict__ xq, ushort_t* __restrict__ xk,
    ushort_t* __restrict__ xv, float* __restrict__ hm, int T)
{
  __shared__ float xs[8][96];
  const int bid = blockIdx.x;
  const int tid = threadIdx.x;
  if (bid < T/8) {                     // ---- mix ----
    const int t0 = bid * 8;
    #pragma unroll
    for (int i = 0; i < 3; i++) {
      const int u = tid + i*256;
      if (u < 768) {
        const int r = u / 96, cc = u % 96;
        xs[r][cc] = xxx[(size_t)(t0+r)*96 + cc];
      }
    }
    __syncthreads();
    const int c = tid * 4;
    float4 xc[8], dx[8];
    #pragma unroll
    for (int r = 0; r < 8; r++) {
      xc[r] = *(const float4*)&x[(size_t)(t0+r)*C_DIM + c];
      dx[r] = *(const float4*)&dxp[(size_t)(t0+r)*C_DIM + c];
    }
    const float* maas[3] = {maa_r, maa_k, maa_v};
    ushort_t* outs[3] = {xq, xk, xv};
    #pragma unroll
    for (int n = 0; n < 3; n++) {
      const float4 mv = *(const float4*)&maas[n][c];
      float m[8][4];
      #pragma unroll
      for (int r = 0; r < 8; r++) {
        m[r][0] = mv.x; m[r][1] = mv.y; m[r][2] = mv.z; m[r][3] = mv.w;
      }
      #pragma unroll 8
      for (int d = 0; d < 32; d++) {
        const float4 w = *(const float4*)&w2[((size_t)n*32 + d)*C_DIM + c];
        #pragma unroll
        for (int r = 0; r < 8; r++) {
          const float xv2 = xs[r][n*32 + d];
          m[r][0] += xv2*w.x; m[r][1] += xv2*w.y;
          m[r][2] += xv2*w.z; m[r][3] += xv2*w.w;
        }
      }
      #pragma unroll
      for (int r = 0; r < 8; r++)
        pack4(&outs[n][(size_t)(t0+r)*C_DIM + c],
              xc[r].x + dx[r].x*m[r][0], xc[r].y + dx[r].y*m[r][1],
              xc[r].z + dx[r].z*m[r][2], xc[r].w + dx[r].w*m[r][3]);
    }
  } else {                             // ---- hm ----
    const int b = bid - T/8;
    const int t = b*4 + (tid >> 6);
    const int u = tid & 63;
    const int n = u >> 4, h = u & 15;
    float s = 0.f;
    #pragma unroll 8
    for (int d = 0; d < 32; d++)
      s += ha[(size_t)t*128 + n*32 + d] * hw2[(size_t)(n*32 + d)*16 + h];
    hm[((size_t)n*T + t)*16 + h] = s * (1.f/16.f);
  }
}

// ---------------- 32x32 GEMM body (R15 dist-1 inner loop) ----------------
__device__ __forceinline__ void gemm_body(
    const ushort_t* __restrict__ A, const ushort_t* __restrict__ Bt,
    float* __restrict__ Cm, int b)
{
  const int bn = (b & 31) * 32;
  const int bm = (b >> 5) * 32;
  const int lane = threadIdx.x;
  const int l15 = lane & 15, g = lane >> 4;
  f32x4 acc[2][2];
  #pragma unroll
  for (int i = 0; i < 2; i++)
    #pragma unroll
    for (int j = 0; j < 2; j++) acc[i][j] = (f32x4){0.f,0.f,0.f,0.f};
  bf16x8 a0[2], b0[2], a1[2], b1[2];
  #define LG(aa, bb, kk) { \
    _Pragma("unroll") \
    for (int i = 0; i < 2; i++) { \
      aa[i] = *(const bf16x8*)&A[(size_t)(bm + i*16 + l15)*C_DIM + (kk) + g*8]; \
      bb[i] = *(const bf16x8*)&Bt[(size_t)(bn + i*16 + l15)*C_DIM + (kk) + g*8]; \
    } }
  LG(a0, b0, 0);
  for (int k0 = 0; k0 < C_DIM; k0 += 64) {
    LG(a1, b1, k0+32);
    #pragma unroll
    for (int i = 0; i < 2; i++)
      #pragma unroll
      for (int j = 0; j < 2; j++) acc[i][j] = MFMA16(a0[i], b0[j], acc[i][j]);
    if (k0 + 64 < C_DIM) LG(a0, b0, k0+64);
    #pragma unroll
    for (int i = 0; i < 2; i++)
      #pragma unroll
      for (int j = 0; j < 2; j++) acc[i][j] = MFMA16(a1[i], b1[j], acc[i][j]);
  }
  #undef LG
  #pragma unroll
  for (int i = 0; i < 2; i++)
    #pragma unroll
    for (int j = 0; j < 2; j++)
      #pragma unroll
      for (int r = 0; r < 4; r++)
        Cm[(size_t)(bm + i*16 + g*4 + r)*C_DIM + bn + j*16 + l15] = acc[i][j][r];
}

// ---------------- K4: fused 3-way QKV GEMM (32x32 tiles) ----------------
__global__ __launch_bounds__(64) void qkv_gemm(
    const ushort_t* __restrict__ xqb, const ushort_t* __restrict__ xkb,
    const ushort_t* __restrict__ xvb,
    const ushort_t* __restrict__ wtr, const ushort_t* __restrict__ wtk,
    const ushort_t* __restrict__ wtv,
    float* __restrict__ oq, float* __restrict__ ok, float* __restrict__ ov)
{
  const int bid = blockIdx.x;
  const int z = bid >> 11, b = bid & 2047;
  const ushort_t* A  = (z == 0) ? xqb : (z == 1) ? xkb : xvb;
  const ushort_t* Bt = (z == 0) ? wtr : (z == 1) ? wtk : wtv;
  float* Cm          = (z == 0) ? oq  : (z == 1) ? ok  : ov;
  gemm_body(A, Bt, Cm, b);
}

// ---------------- K12: single GEMM (final projection, 32x32) ---------------
__global__ __launch_bounds__(64) void gemm_bf16(
    const ushort_t* __restrict__ A, const ushort_t* __restrict__ Bt,
    float* __restrict__ Cm)
{
  gemm_body(A, Bt, Cm, blockIdx.x);
}

// ---------------- K5: fused 3-way LayerNorm -> bf16 ----------------
__global__ __launch_bounds__(256) void ln3_rows(
    const float* __restrict__ iq, const float* __restrict__ ik,
    const float* __restrict__ iv,
    ushort_t* __restrict__ oq, ushort_t* __restrict__ ok,
    ushort_t* __restrict__ ov,
    const float* __restrict__ gq, const float* __restrict__ bq,
    const float* __restrict__ gk, const float* __restrict__ bk,
    const float* __restrict__ gv, const float* __restrict__ bv2, int T)
{
  __shared__ float red[4];
  const int bid = blockIdx.x;
  const int z = bid / T, t = bid - z*T;
  const float* in = (z == 0) ? iq : (z == 1) ? ik : iv;
  ushort_t* outp  = (z == 0) ? oq : (z == 1) ? ok : ov;
  const float* g  = (z == 0) ? gq : (z == 1) ? gk : gv;
  const float* b  = (z == 0) ? bq : (z == 1) ? bk : bv2;
  const float scale = (z == 0) ? 0.125f : 1.0f;
  const int tid = threadIdx.x;
  const int c = tid*4;
  const float4 v = *(const float4*)&in[(size_t)t*C_DIM + c];
  float s = v.x+v.y+v.z+v.w;
  #pragma unroll
  for (int off = 32; off > 0; off >>= 1) s += __shfl_down(s, off, 64);
  if ((tid & 63) == 0) red[tid >> 6] = s;
  __syncthreads();
  const float mean = (red[0]+red[1]+red[2]+red[3]) * (1.0f/C_DIM);
  __syncthreads();
  const float d0 = v.x-mean, d1 = v.y-mean, d2 = v.z-mean, d3 = v.w-mean;
  float q = d0*d0 + d1*d1 + d2*d2 + d3*d3;
  #pragma unroll
  for (int off = 32; off > 0; off >>= 1) q += __shfl_down(q, off, 64);
  if ((tid & 63) == 0) red[tid >> 6] = q;
  __syncthreads();
  const float var = (red[0]+red[1]+red[2]+red[3]) * (1.0f/C_DIM);
  const float rstd = rsqrtf(var + 1e-5f);
  const float4 gv4 = *(const float4*)&g[c];
  const float4 bv4 = *(const float4*)&b[c];
  pack4(outp + (size_t)t*C_DIM + c,
        (d0*rstd*gv4.x + bv4.x)*scale, (d1*rstd*gv4.y + bv4.y)*scale,
        (d2*rstd*gv4.z + bv4.z)*scale, (d3*rstd*gv4.w + bv4.w)*scale);
}

// ---------------- K6: vtrans + qek_prep ----------------
__global__ __launch_bounds__(256) void vtrans_qek(
    const ushort_t* __restrict__ vbf, ushort_t* __restrict__ Vt,
    const ushort_t* __restrict__ qbf, const ushort_t* __restrict__ kbf,
    const float* __restrict__ hmb, ushort_t* __restrict__ Qe,
    ushort_t* __restrict__ Ke, float* __restrict__ spo_g, int T)
{
  __shared__ ushort_t tile[32][36];
  const int bid = blockIdx.x;
  const int tid = threadIdx.x;
  const int NV = (T/32) * (C_DIM/32);   // 2048
  if (bid < NV) {                      // ---- vtrans ----
    const int t0 = (bid & 63) * 32, c0 = (bid >> 6) * 32;
    const int r = tid >> 3, c4 = (tid & 7) * 4;
    const uint2 raw = *(const uint2*)&vbf[(size_t)(t0+r)*C_DIM + c0 + c4];
    tile[r][c4+0] = (ushort_t)(raw.x & 0xffffu);
    tile[r][c4+1] = (ushort_t)(raw.x >> 16);
    tile[r][c4+2] = (ushort_t)(raw.y & 0xffffu);
    tile[r][c4+3] = (ushort_t)(raw.y >> 16);
    __syncthreads();
    uint2 w;
    w.x = (unsigned)tile[c4+0][r] | ((unsigned)tile[c4+1][r] << 16);
    w.y = (unsigned)tile[c4+2][r] | ((unsigned)tile[c4+3][r] << 16);
    *(uint2*)&Vt[(size_t)(c0+r)*T + t0 + c4] = w;
  } else {                             // ---- qek_prep ----
    const int t = bid - NV;
    const int c4 = tid * 4;
    const int h = tid >> 4;
    float sp = 0.f, so = 0.f;
    #pragma unroll
    for (int q4 = 0; q4 < 4; q4++) {
      const float4 v = *(const float4*)&hmb[((size_t)1*T + t)*16 + q4*4];
      sp += v.x + v.y + v.z + v.w;
      const float4 o = *(const float4*)&hmb[((size_t)3*T + t)*16 + q4*4];
      so += o.x + o.y + o.z + o.w;
    }
    if (tid == 0) spo_g[t] = so;
    const float preq = hmb[((size_t)0*T + t)*16 + h];
    const float prek = hmb[((size_t)1*T + t)*16 + h];
    const uint2 qr = *(const uint2*)&qbf[(size_t)t*C_DIM + c4];
    const uint2 kr = *(const uint2*)&kbf[(size_t)t*C_DIM + c4];
    float qv[4], kv[4];
    qv[0] = bf2f((ushort_t)(qr.x & 0xffffu)); qv[1] = bf2f((ushort_t)(qr.x >> 16));
    qv[2] = bf2f((ushort_t)(qr.y & 0xffffu)); qv[3] = bf2f((ushort_t)(qr.y >> 16));
    kv[0] = bf2f((ushort_t)(kr.x & 0xffffu)); kv[1] = bf2f((ushort_t)(kr.x >> 16));
    kv[2] = bf2f((ushort_t)(kr.y & 0xffffu)); kv[3] = bf2f((ushort_t)(kr.y >> 16));
    const size_t rb = (size_t)t * 2048;
    pack4(&Qe[rb + c4], qv[0]*preq, qv[1]*preq, qv[2]*preq, qv[3]*preq);
    *(uint2*)&Qe[rb + 1024 + c4] = qr;
    const float osp = 1.f + sp;
    pack4(&Ke[rb + c4], kv[0]*osp, kv[1]*osp, kv[2]*osp, kv[3]*osp);
    pack4(&Ke[rb + 1024 + c4], kv[0]*prek, kv[1]*prek, kv[2]*prek, kv[3]*prek);
  }
}

// ---------------- K7: E GEMM (32x32 causal tiles, K=2048, dist-1) ----------
__global__ __launch_bounds__(64) void e_gemm(
    const ushort_t* __restrict__ Qe, const ushort_t* __restrict__ Ke,
    float* __restrict__ E, int T)
{
  if ((int)blockIdx.x > (int)blockIdx.y) return;   // fully-masked tile
  const int bm = blockIdx.y * 32;
  const int bn = blockIdx.x * 32;
  const int lane = threadIdx.x;
  const int l15 = lane & 15, g = lane >> 4;
  const int KD = 2048;
  f32x4 acc[2][2];
  #pragma unroll
  for (int i = 0; i < 2; i++)
    #pragma unroll
    for (int j = 0; j < 2; j++) acc[i][j] = (f32x4){0.f,0.f,0.f,0.f};
  bf16x8 a0[2], b0[2], a1[2], b1[2];
  #define LE(aa, bb, kk) { \
    _Pragma("unroll") \
    for (int i = 0; i < 2; i++) { \
      aa[i] = *(const bf16x8*)&Qe[(size_t)(bm + i*16 + l15)*KD + (kk) + g*8]; \
      bb[i] = *(const bf16x8*)&Ke[(size_t)(bn + i*16 + l15)*KD + (kk) + g*8]; \
    } }
  LE(a0, b0, 0);
  for (int k0 = 0; k0 < KD; k0 += 64) {
    LE(a1, b1, k0+32);
    #pragma unroll
    for (int i = 0; i < 2; i++)
      #pragma unroll
      for (int j = 0; j < 2; j++) acc[i][j] = MFMA16(a0[i], b0[j], acc[i][j]);
    if (k0 + 64 < KD) LE(a0, b0, k0+64);
    #pragma unroll
    for (int i = 0; i < 2; i++)
      #pragma unroll
      for (int j = 0; j < 2; j++) acc[i][j] = MFMA16(a1[i], b1[j], acc[i][j]);
  }
  #undef LE
  #pragma unroll
  for (int i = 0; i < 2; i++)
    #pragma unroll
    for (int j = 0; j < 2; j++)
      #pragma unroll
      for (int r = 0; r < 4; r++)
        E[(size_t)(bm + i*16 + g*4 + r)*T + bn + j*16 + l15] = acc[i][j][r];
}

// ---------------- K8: pass 1 = scores + fixed-M l + y3 dump ----------------
__global__ __launch_bounds__(512) void attn_stats(
    const ushort_t* __restrict__ qbf, const ushort_t* __restrict__ kbf,
    const float* __restrict__ E, float* __restrict__ part_l,
    ushort_t* __restrict__ y3d, int T)
{
  const int tbi = (int)blockIdx.y;
  const int tb = (T/TQ) - 1 - tbi;
  const int sc = (tbi & 1) ? (7 - (int)blockIdx.x) : (int)blockIdx.x;
  const int t0 = tb * TQ;
  const int sbeg = sc * SCH;
  if (sbeg >= t0 + TQ) return;
  const int send = (sbeg + SCH < t0 + TQ) ? (sbeg + SCH) : (t0 + TQ);
  const int offT = y3_off(tbi);

  const int tid = threadIdx.x;
  const int w = tid >> 6, lane = tid & 63, l15 = lane & 15, g = lane >> 4;
  const int hh[2] = {w, w + 8};
  bf16x8 qf[2][2];
  float slope[2];
  #pragma unroll
  for (int hd = 0; hd < 2; hd++) {
    #pragma unroll
    for (int kc = 0; kc < 2; kc++)
      qf[hd][kc] = *(const bf16x8*)
          &qbf[(size_t)(t0 + l15)*C_DIM + hh[hd]*64 + kc*32 + g*8];
    slope[hd] = exp2f(-0.5f * (float)(hh[hd] + 1));
  }
  float lrun[2] = {0.f, 0.f};

  bf16x8 kf[2][2][2];
  float4 ef[2];
  #define LOADK(sbase) { \
    _Pragma("unroll") \
    for (int hd = 0; hd < 2; hd++) \
      _Pragma("unroll") \
      for (int sh = 0; sh < 2; sh++) \
        _Pragma("unroll") \
        for (int kc = 0; kc < 2; kc++) \
          kf[hd][sh][kc] = *(const bf16x8*)&kbf[ \
              (size_t)((sbase) + sh*16 + l15)*C_DIM + hh[hd]*64 + kc*32 + g*8]; }
  #define LOADE(sbase) { \
    _Pragma("unroll") \
    for (int sh = 0; sh < 2; sh++) \
      ef[sh] = *(const float4*)&E[(size_t)(t0 + l15)*T + (sbase) + sh*16 + g*4]; }
  LOADK(sbeg); LOADE(sbeg);

  for (int s1 = sbeg; s1 < send; s1 += 32) {
    f32x4 acc[2][2];
    #pragma unroll
    for (int hd = 0; hd < 2; hd++)
      #pragma unroll
      for (int sh = 0; sh < 2; sh++) acc[hd][sh] = (f32x4){0.f,0.f,0.f,0.f};
    #pragma unroll
    for (int hd = 0; hd < 2; hd++)
      #pragma unroll
      for (int sh = 0; sh < 2; sh++)
        #pragma unroll
        for (int kc = 0; kc < 2; kc++)
          acc[hd][sh] = MFMA16(kf[hd][sh][kc], qf[hd][kc], acc[hd][sh]);
    float efc[2][4];
    #pragma unroll
    for (int sh = 0; sh < 2; sh++) *(float4*)efc[sh] = ef[sh];
    {
      const int snx = (s1 + 32 < send) ? s1 + 32 : s1;
      LOADK(snx); LOADE(snx);
    }
    ushort_t* slot = y3d + ((size_t)(offT + (s1 >> 5))*512 + tid)*16;
    #pragma unroll
    for (int hd = 0; hd < 2; hd++) {
      const int t = t0 + l15;
      #pragma unroll
      for (int sh = 0; sh < 2; sh++) {
        float y3v[4];
        #pragma unroll
        for (int r = 0; r < 4; r++) {
          const int s = s1 + sh*16 + g*4 + r;
          y3v[r] = acc[hd][sh][r] + efc[sh][r] - slope[hd]*(float)(t - s);
          lrun[hd] += (s <= t) ? __expf(y3v[r] - FIXED_M) : 0.f;
        }
        __half2 h0 = __floats2half2_rn(y3v[0], y3v[1]);
        __half2 h1 = __floats2half2_rn(y3v[2], y3v[3]);
        uint2 pk;
        pk.x = *(unsigned*)&h0;
        pk.y = *(unsigned*)&h1;
        *(uint2*)(slot + (hd*2 + sh)*4) = pk;
      }
    }
  }
  #undef LOADK
  #undef LOADE
  #pragma unroll
  for (int hd = 0; hd < 2; hd++) {
    float L = lrun[hd];
    L += __shfl_xor(L, 16, 64);
    L += __shfl_xor(L, 32, 64);
    if (g == 0)
      part_l[(size_t)(sc*HEADS + hh[hd])*T + t0 + l15] = L;
  }
}

// ---------------- K10: pass 2 = apply from y3 (top-of-loop mem issue) ------
__global__ __launch_bounds__(512) void attn_apply(
    const ushort_t* __restrict__ y3d, const ushort_t* __restrict__ Vt,
    const float* __restrict__ hmb, const float* __restrict__ spo_g,
    const float* __restrict__ part_l, float* __restrict__ P, int T)
{
  __shared__ ushort_t ybuf[HEADS*TQ*PADS];   // 20.5 KB
  __shared__ float ep[TQ*EPS];               // 2.3 KB

  const int tbi = (int)blockIdx.y;
  const int tb = (T/TQ) - 1 - tbi;
  const int sc = (tbi & 1) ? (7 - (int)blockIdx.x) : (int)blockIdx.x;
  const int t0 = tb * TQ;
  const int sbeg = sc * SCH;
  if (sbeg >= t0 + TQ) return;
  const int send = (sbeg + SCH < t0 + TQ) ? (sbeg + SCH) : (t0 + TQ);
  const int prow0 = T*sc - 128*sc*(sc-1) - SCH*sc;
  const int offT = y3_off(tbi);

  const int tid = threadIdx.x;
  const int w = tid >> 6, lane = tid & 63, l15 = lane & 15, g = lane >> 4;
  const int hh[2] = {w, w + 8};
  float li[2];
  const int nsc = (t0 >> 8) + 1;
  #pragma unroll
  for (int hd = 0; hd < 2; hd++) {
    float l = 0.f;
    for (int s2 = 0; s2 < nsc; s2++)
      l += part_l[(size_t)(s2*HEADS + hh[hd])*T + t0 + l15];
    li[hd] = 1.f / l;
  }
  f32x4 oacc[2][4];
  #pragma unroll
  for (int hd = 0; hd < 2; hd++)
    #pragma unroll
    for (int vf = 0; vf < 4; vf++) oacc[hd][vf] = (f32x4){0.f,0.f,0.f,0.f};

  // prefetch first y3 block into registers
  uint2 pk[2][2];
  {
    const ushort_t* slot = y3d + ((size_t)(offT + (sbeg >> 5))*512 + tid)*16;
    #pragma unroll
    for (int hd = 0; hd < 2; hd++)
      #pragma unroll
      for (int sh = 0; sh < 2; sh++)
        pk[hd][sh] = *(const uint2*)(slot + (hd*2 + sh)*4);
  }

  for (int s1 = sbeg; s1 < send; s1 += 32) {
    // ---- issue ALL independent memory at the top of the iteration ----
    bf16x8 vv[2][4];
    #pragma unroll
    for (int hd = 0; hd < 2; hd++)
      #pragma unroll
      for (int vf = 0; vf < 4; vf++)
        vv[hd][vf] = *(const bf16x8*)
            &Vt[(size_t)(hh[hd]*64 + vf*16 + l15)*T + s1 + g*8];
    uint2 pknext[2][2];
    if (s1 + 32 < send) {
      const ushort_t* slot =
          y3d + ((size_t)(offT + ((s1 + 32) >> 5))*512 + tid)*16;
      #pragma unroll
      for (int hd = 0; hd < 2; hd++)
        #pragma unroll
        for (int sh = 0; sh < 2; sh++)
          pknext[hd][sh] = *(const uint2*)(slot + (hd*2 + sh)*4);
    }
    // ---- p = exp(y3 - M) * li  (from prefetched pk) ----
    f32x4 acc[2][2];
    #pragma unroll
    for (int hd = 0; hd < 2; hd++) {
      const int t = t0 + l15;
      #pragma unroll
      for (int sh = 0; sh < 2; sh++) {
        const float2 f0 = __half22float2(*(const __half2*)&pk[hd][sh].x);
        const float2 f1 = __half22float2(*(const __half2*)&pk[hd][sh].y);
        const float y3v[4] = {f0.x, f0.y, f1.x, f1.y};
        #pragma unroll
        for (int r = 0; r < 4; r++) {
          const int s = s1 + sh*16 + g*4 + r;
          float p = 0.f;
          if (s <= t) p = __expf(y3v[r] - FIXED_M) * li[hd];
          acc[hd][sh][r] = p;
        }
        pack4(&ybuf[(size_t)(hh[hd]*TQ + l15)*PADS + sh*16 + g*4],
              acc[hd][sh][0], acc[hd][sh][1], acc[hd][sh][2], acc[hd][sh][3]);
      }
    }
    __syncthreads();                     // bar1: p ready
    // e_post: ALL 512 threads, one (tc,scell) cell each
    {
      const int tc = tid >> 5, scell = tid & 31;
      const int s0g = s1 + scell;
      float a = 0.f, b = 0.f;
      #pragma unroll
      for (int h4 = 0; h4 < 4; h4++) {
        const float4 hq4 = *(const float4*)&hmb[((size_t)2*T + t0 + tc)*16 + h4*4];
        const float4 hk4 = *(const float4*)&hmb[((size_t)3*T + s0g)*16 + h4*4];
        const float hqa[4] = {hq4.x, hq4.y, hq4.z, hq4.w};
        const float hka[4] = {hk4.x, hk4.y, hk4.z, hk4.w};
        #pragma unroll
        for (int j = 0; j < 4; j++) {
          const float y = bf2f(ybuf[((h4*4 + j)*TQ + tc)*PADS + scell]);
          a += y * hqa[j];
          b += y * hka[j];
        }
      }
      ep[tc*EPS + scell] = a*(1.f + spo_g[s0g]) + b;
    }
    __syncthreads();                     // bar2: ep ready; ybuf reads done
    // p2 = p + e_post, pack, PV  (vv already resident)
    {
      float epv[2][4];
      #pragma unroll
      for (int sh = 0; sh < 2; sh++)
        *(float4*)epv[sh] = *(const float4*)&ep[l15*EPS + sh*16 + g*4];
      #pragma unroll
      for (int hd = 0; hd < 2; hd++)
        #pragma unroll
        for (int sh = 0; sh < 2; sh++)
          pack4(&ybuf[(size_t)(hh[hd]*TQ + l15)*PADS + sh*16 + g*4],
                acc[hd][sh][0] + epv[sh][0], acc[hd][sh][1] + epv[sh][1],
                acc[hd][sh][2] + epv[sh][2], acc[hd][sh][3] + epv[sh][3]);
    }
    #pragma unroll
    for (int hd = 0; hd < 2; hd++) {
      const bf16x8 pa = *(const bf16x8*)
          &ybuf[(size_t)(hh[hd]*TQ + l15)*PADS + g*8];   // wave-local rows
      #pragma unroll
      for (int vf = 0; vf < 4; vf++)
        oacc[hd][vf] = MFMA16(pa, vv[hd][vf], oacc[hd][vf]);
    }
    #pragma unroll
    for (int hd = 0; hd < 2; hd++)
      #pragma unroll
      for (int sh = 0; sh < 2; sh++)
        pk[hd][sh] = pknext[hd][sh];
  }
  #pragma unroll
  for (int hd = 0; hd < 2; hd++)
    #pragma unroll
    for (int vf = 0; vf < 4; vf++)
      #pragma unroll
      for (int r = 0; r < 4; r++)
        P[(size_t)(prow0 + t0 + g*4 + r)*C_DIM + hh[hd]*64 + vf*16 + l15]
            = oacc[hd][vf][r];
}

// ---------------- K11: reduce partials + LayerNorm -> bf16 -----------------
__global__ __launch_bounds__(256) void reduce_ln(
    const float* __restrict__ P, ushort_t* __restrict__ outp,
    const float* __restrict__ g, const float* __restrict__ b, int T)
{
  __shared__ float red[4];
  const int t = blockIdx.x;
  const int tid = threadIdx.x;
  const int c = tid*4;
  const int nsc = (t >> 8) + 1;
  float4 v = make_float4(0.f, 0.f, 0.f, 0.f);
  int off = 0;
  for (int sc = 0; sc < nsc; sc++) {
    const int row = off + t - sc*SCH;
    const float4 pv = *(const float4*)&P[(size_t)row*C_DIM + c];
    v.x += pv.x; v.y += pv.y; v.z += pv.z; v.w += pv.w;
    off += T - SCH*sc;
  }
  float s = v.x+v.y+v.z+v.w;
  #pragma unroll
  for (int o = 32; o > 0; o >>= 1) s += __shfl_down(s, o, 64);
  if ((tid & 63) == 0) red[tid >> 6] = s;
  __syncthreads();
  const float mean = (red[0]+red[1]+red[2]+red[3]) * (1.0f/C_DIM);
  __syncthreads();
  const float d0 = v.x-mean, d1 = v.y-mean, d2 = v.z-mean, d3 = v.w-mean;
  float q = d0*d0 + d1*d1 + d2*d2 + d3*d3;
  #pragma unroll
  for (int o = 32; o > 0; o >>= 1) q += __shfl_down(q, o, 64);
  if ((tid & 63) == 0) red[tid >> 6] = q;
  __syncthreads();
  const float var = (red[0]+red[1]+red[2]+red[3]) * (1.0f/C_DIM);
  const float rstd = rsqrtf(var + 1e-5f);
  const float4 gv = *(const float4*)&g[c];
  const float4 bv = *(const float4*)&b[c];
  pack4(outp + (size_t)t*C_DIM + c,
        d0*rstd*gv.x + bv.x, d1*rstd*gv.y + bv.y,
        d2*rstd*gv.z + bv.z, d3*rstd*gv.w + bv.w);
}

// ---------------- launcher ----------------
extern "C" void kernel_launch(void* const* d_in, const int* in_sizes, int n_in,
                              void* d_out, int out_size, void* d_ws, size_t ws_size,
                              hipStream_t stream)
{
  const float* x      = (const float*)d_in[0];
  const float* shift  = (const float*)d_in[1];
  const float* maa_x  = (const float*)d_in[2];
  const float* maa_r  = (const float*)d_in[3];
  const float* maa_k  = (const float*)d_in[4];
  const float* maa_v  = (const float*)d_in[5];
  const float* w1     = (const float*)d_in[6];
  const float* w2     = (const float*)d_in[7];
  const float* hw1    = (const float*)d_in[8];
  const float* hw2    = (const float*)d_in[9];
  const float* w_r    = (const float*)d_in[10];
  const float* w_k    = (const float*)d_in[11];
  const float* w_v    = (const float*)d_in[12];
  const float* w_o    = (const float*)d_in[13];
  const float* ln_r_g = (const float*)d_in[14];
  const float* ln_r_b = (const float*)d_in[15];
  const float* ln_k_g = (const float*)d_in[16];
  const float* ln_k_b = (const float*)d_in[17];
  const float* ln_v_g = (const float*)d_in[18];
  const float* ln_v_b = (const float*)d_in[19];
  const float* ln_x_g = (const float*)d_in[20];
  const float* ln_x_b = (const float*)d_in[21];

  const int T = in_sizes[0] / C_DIM;            // 2048
  const size_t MM = (size_t)T * C_DIM;          // 2M f32 elems
  const size_t HF = MM / 2;

  float* ws = (float*)d_ws;
  float*    P      = ws;
  float*    dxprev = ws;
  ushort_t* zbf    = (ushort_t*)(ws + MM);
  ushort_t* xbf    = (ushort_t*)(ws + MM + HF);
  float*    gtmpQ  = ws;
  float*    gtmpK  = ws + MM;
  float*    gtmpV  = ws + 2*MM;
  ushort_t* xqb    = (ushort_t*)(ws + 3*MM);
  ushort_t* xkb    = (ushort_t*)(ws + 3*MM + HF);
  ushort_t* xvb    = (ushort_t*)(ws + 4*MM);
  ushort_t* Qe     = (ushort_t*)ws;
  ushort_t* Ke     = (ushort_t*)(ws + MM);
  float* base2 = ws + 4*MM + HF;                  // = 4.5*MM
  ushort_t* qbf = (ushort_t*)(base2 + 0*HF);
  ushort_t* kbf = (ushort_t*)(base2 + 1*HF);
  ushort_t* vbf = (ushort_t*)(base2 + 2*HF);
  ushort_t* Vt  = (ushort_t*)(base2 + 3*HF);
  ushort_t* wtr = (ushort_t*)(base2 + 4*HF);
  ushort_t* wtk = wtr + (size_t)C_DIM*C_DIM;
  ushort_t* wtv = wtk + (size_t)C_DIM*C_DIM;
  ushort_t* wto = wtv + (size_t)C_DIM*C_DIM;
  float* after_w = base2 + 4*HF + (size_t)2*C_DIM*C_DIM;
  ushort_t* wlt = (ushort_t*)after_w;             // 224*1024 bf16
  float* xxx    = after_w + 131072;               // T*96
  float* ha     = xxx + (size_t)T*96;             // T*128
  float* hmb    = ha + (size_t)T*128;             // 4*T*16
  float* part_l = hmb + (size_t)4*T*16;           // 8*HEADS*T
  float* spo_g  = part_l + (size_t)8*HEADS*T;     // T
  float* abf_f  = spo_g + (size_t)T;
  ushort_t* abf = (ushort_t*)abf_f;               // HF
  float* Ebuf   = abf_f + HF;                     // T*T f32
  ushort_t* y3d = (ushort_t*)(Ebuf + (size_t)T*T);  // ~68 MB fp16

  prep_all<<<T + 224 + 4096, 256, 0, stream>>>(
      x, shift, maa_x, dxprev, zbf, xbf, w1, hw1, wlt,
      w_r, w_k, w_v, w_o, wtr, wtk, wtv, wto, T);
  lora_gemm<<<dim3(T/32, 7), 64, 0, stream>>>(zbf, xbf, wlt, xxx, ha);
  mix_hm<<<T/8 + T/4, 256, 0, stream>>>(x, dxprev, xxx, ha,
      maa_r, maa_k, maa_v, w2, hw2, xqb, xkb, xvb, hmb, T);
  qkv_gemm<<<3*2048, 64, 0, stream>>>(xqb, xkb, xvb, wtr, wtk, wtv,
                                      gtmpQ, gtmpK, gtmpV);
  ln3_rows<<<3*T, 256, 0, stream>>>(gtmpQ, gtmpK, gtmpV, qbf, kbf, vbf,
      ln_r_g, ln_r_b, ln_k_g, ln_k_b, ln_v_g, ln_v_b, T);
  vtrans_qek<<<(T/32)*(C_DIM/32) + T, 256, 0, stream>>>(
      vbf, Vt, qbf, kbf, hmb, Qe, Ke, spo_g, T);
  e_gemm<<<dim3(T/32, T/32), 64, 0, stream>>>(Qe, Ke, Ebuf, T);
  attn_stats<<<dim3(8, T/TQ), 512, 0, stream>>>(
      qbf, kbf, Ebuf, part_l, y3d, T);
  attn_apply<<<dim3(8, T/TQ), 512, 0, stream>>>(
      y3d, Vt, hmb, spo_g, part_l, P, T);
  reduce_ln<<<T, 256, 0, stream>>>(P, abf, ln_x_g, ln_x_b, T);
  gemm_bf16<<<(T/32)*(C_DIM/32), 64, 0, stream>>>(abf, wto, (float*)d_out);
}

// Round 19
// 470.976 us; speedup vs baseline: 1.1132x; 1.1132x over previous
//
#include <hip/hip_runtime.h>
#include <hip/hip_fp16.h>
#include <cstdint>
#include <cstddef>

// RWKV_Tmix_headmixer — round 19: revert to R15 champion (470 us).
// R16 (dist-2 runtime-indexed) -> scratch catastrophe; R17 (static dist-2)
// -> neutral-minus; R18 (32x32 tiles) -> e_gemm HBM-bound (reuse loss).
// R15 = dist-1 double-buffered 32x64 GEMMs + y3 dump/reload attention with
// top-of-loop memory issue. This is the measured optimum.
// B=1, T=2048, C=1024, H=16, K=64.

#define C_DIM 1024
#define HEADS 16
#define TQ 16
#define SCH 256
#define PADS 40
#define EPS 36
#define FIXED_M 40.0f

typedef unsigned short ushort_t;
typedef __attribute__((ext_vector_type(8))) short bf16x8;
typedef __attribute__((ext_vector_type(4))) float f32x4;

#define MFMA16(a, b, c) __builtin_amdgcn_mfma_f32_16x16x32_bf16(a, b, c, 0, 0, 0)

__device__ __forceinline__ unsigned int f2bf_u(float f) {
  unsigned int u = __float_as_uint(f);
  return (u + 0x7fffu + ((u >> 16) & 1u)) >> 16;   // RNE
}
__device__ __forceinline__ float bf2f(ushort_t u) {
  return __uint_as_float(((unsigned int)u) << 16);
}
__device__ __forceinline__ void pack4(ushort_t* dst, float x0, float x1,
                                      float x2, float x3) {
  uint2 v;
  v.x = f2bf_u(x0) | (f2bf_u(x1) << 16);
  v.y = f2bf_u(x2) | (f2bf_u(x3) << 16);
  *(uint2*)dst = v;
}
// packed y3 tile-slot offset: ntiles(tbi) = ceil((t0+16)/32), t0=(127-tbi)*16
__device__ __forceinline__ int y3_off(int tbi) {
  const int m = tbi >> 1;
  const int S = m*(m-1) + ((tbi & 1) ? m : 0);
  return 64*tbi - S;
}

// ---------------- K1: prep_all = prep + wlora_prep + wprep(x4) -------------
__global__ __launch_bounds__(256) void prep_all(
    const float* __restrict__ x, const float* __restrict__ shift,
    const float* __restrict__ maa_x,
    float* __restrict__ dxprev, ushort_t* __restrict__ zbf,
    ushort_t* __restrict__ xbf,
    const float* __restrict__ w1, const float* __restrict__ hw1,
    ushort_t* __restrict__ wlt,
    const float* __restrict__ w_r, const float* __restrict__ w_k,
    const float* __restrict__ w_v, const float* __restrict__ w_o,
    ushort_t* __restrict__ wtr, ushort_t* __restrict__ wtk,
    ushort_t* __restrict__ wtv, ushort_t* __restrict__ wto, int T)
{
  __shared__ float tile[32][33];
  const int bid = blockIdx.x;
  const int tid = threadIdx.x;
  if (bid < T) {                       // ---- prep ----
    const int t = bid;
    const int c = tid * 4;
    const size_t base = (size_t)t * C_DIM + c;
    const float4 xc = *(const float4*)&x[base];
    const float4 xp = (t == 0) ? *(const float4*)&shift[c]
                               : *(const float4*)&x[base - C_DIM];
    const float4 mx = *(const float4*)&maa_x[c];
    float4 d;
    d.x = xp.x - xc.x; d.y = xp.y - xc.y; d.z = xp.z - xc.z; d.w = xp.w - xc.w;
    *(float4*)&dxprev[base] = d;
    pack4(&zbf[base], xc.x + d.x*mx.x, xc.y + d.y*mx.y,
          xc.z + d.z*mx.z, xc.w + d.w*mx.w);
    pack4(&xbf[base], xc.x, xc.y, xc.z, xc.w);
  } else if (bid < T + 224) {          // ---- wlora_prep ----
    const int b = bid - T;
    const int k0 = (b & 31) * 32, j0 = (b >> 5) * 32;
    const int r = tid >> 3, c4 = (tid & 7) * 4;
    const float* W = (j0 < 96) ? w1 : hw1;
    const int stride = (j0 < 96) ? 96 : 128;
    const int jo = (j0 < 96) ? j0 : j0 - 96;
    const float4 v = *(const float4*)&W[(size_t)(k0+r)*stride + jo + c4];
    tile[r][c4+0] = v.x; tile[r][c4+1] = v.y;
    tile[r][c4+2] = v.z; tile[r][c4+3] = v.w;
    __syncthreads();
    pack4(&wlt[(size_t)(j0+r)*C_DIM + k0 + c4],
          tile[c4+0][r], tile[c4+1][r], tile[c4+2][r], tile[c4+3][r]);
  } else {                             // ---- wprep x4 ----
    const int b = bid - T - 224;
    const int z = b >> 10, rr = b & 1023;
    const int k0 = (rr & 31) * 32, n0 = (rr >> 5) * 32;
    const float* W; ushort_t* O;
    if (z == 0)      { W = w_r; O = wtr; }
    else if (z == 1) { W = w_k; O = wtk; }
    else if (z == 2) { W = w_v; O = wtv; }
    else             { W = w_o; O = wto; }
    const int r = tid >> 3, c4 = (tid & 7) * 4;
    const float4 v = *(const float4*)&W[(size_t)(k0+r)*C_DIM + n0 + c4];
    tile[r][c4+0] = v.x; tile[r][c4+1] = v.y;
    tile[r][c4+2] = v.z; tile[r][c4+3] = v.w;
    __syncthreads();
    pack4(&O[(size_t)(n0+r)*C_DIM + k0 + c4],
          tile[c4+0][r], tile[c4+1][r], tile[c4+2][r], tile[c4+3][r]);
  }
}

// ---------------- K2: lora GEMM with tanh epilogue ----------------
__global__ __launch_bounds__(64) void lora_gemm(
    const ushort_t* __restrict__ zbf, const ushort_t* __restrict__ xbf,
    const ushort_t* __restrict__ wlt, float* __restrict__ xxx,
    float* __restrict__ ha)
{
  const int nt = blockIdx.y;
  const int bm = blockIdx.x * 32;
  const ushort_t* A = (nt < 3) ? zbf : xbf;
  const int wrow = nt * 32;
  const int lane = threadIdx.x;
  const int l15 = lane & 15, g = lane >> 4;
  f32x4 acc[2][2];
  #pragma unroll
  for (int i = 0; i < 2; i++)
    #pragma unroll
    for (int j = 0; j < 2; j++) acc[i][j] = (f32x4){0.f,0.f,0.f,0.f};
  bf16x8 a0[2], b0[2], a1[2], b1[2];
  #define LLA(aa, bb, kk) { \
    _Pragma("unroll") \
    for (int i = 0; i < 2; i++) { \
      aa[i] = *(const bf16x8*)&A[(size_t)(bm + i*16 + l15)*C_DIM + (kk) + g*8]; \
      bb[i] = *(const bf16x8*)&wlt[(size_t)(wrow + i*16 + l15)*C_DIM + (kk) + g*8]; \
    } }
  LLA(a0, b0, 0);
  for (int k0 = 0; k0 < C_DIM; k0 += 64) {
    LLA(a1, b1, k0+32);
    #pragma unroll
    for (int i = 0; i < 2; i++)
      #pragma unroll
      for (int j = 0; j < 2; j++) acc[i][j] = MFMA16(a0[i], b0[j], acc[i][j]);
    if (k0 + 64 < C_DIM) LLA(a0, b0, k0+64);
    #pragma unroll
    for (int i = 0; i < 2; i++)
      #pragma unroll
      for (int j = 0; j < 2; j++) acc[i][j] = MFMA16(a1[i], b1[j], acc[i][j]);
  }
  #undef LLA
  #pragma unroll
  for (int i = 0; i < 2; i++)
    #pragma unroll
    for (int j = 0; j < 2; j++)
      #pragma unroll
      for (int r = 0; r < 4; r++) {
        const int t = bm + i*16 + g*4 + r;
        const int col = wrow + j*16 + l15;
        const float val = tanhf(acc[i][j][r]);
        if (nt < 3) xxx[(size_t)t*96 + col] = val;
        else        ha[(size_t)t*128 + col - 96] = val;
      }
}

// ---------------- K3: mix + hm ----------------
__global__ __launch_bounds__(256) void mix_hm(
    const float* __restrict__ x, const float* __restrict__ dxp,
    const float* __restrict__ xxx, const float* __restrict__ ha,
    const float* __restrict__ maa_r, const float* __restrict__ maa_k,
    const float* __restrict__ maa_v, const float* __restrict__ w2,
    const float* __restrict__ hw2,
    ushort_t* __restrict__ xq, ushort_t* __restrict__ xk,
    ushort_t* __restrict__ xv, float* __restrict__ hm, int T)
{
  __shared__ float xs[8][96];
  const int bid = blockIdx.x;
  const int tid = threadIdx.x;
  if (bid < T/8) {                     // ---- mix ----
    const int t0 = bid * 8;
    #pragma unroll
    for (int i = 0; i < 3; i++) {
      const int u = tid + i*256;
      if (u < 768) {
        const int r = u / 96, cc = u % 96;
        xs[r][cc] = xxx[(size_t)(t0+r)*96 + cc];
      }
    }
    __syncthreads();
    const int c = tid * 4;
    float4 xc[8], dx[8];
    #pragma unroll
    for (int r = 0; r < 8; r++) {
      xc[r] = *(const float4*)&x[(size_t)(t0+r)*C_DIM + c];
      dx[r] = *(const float4*)&dxp[(size_t)(t0+r)*C_DIM + c];
    }
    const float* maas[3] = {maa_r, maa_k, maa_v};
    ushort_t* outs[3] = {xq, xk, xv};
    #pragma unroll
    for (int n = 0; n < 3; n++) {
      const float4 mv = *(const float4*)&maas[n][c];
      float m[8][4];
      #pragma unroll
      for (int r = 0; r < 8; r++) {
        m[r][0] = mv.x; m[r][1] = mv.y; m[r][2] = mv.z; m[r][3] = mv.w;
      }
      #pragma unroll 8
      for (int d = 0; d < 32; d++) {
        const float4 w = *(const float4*)&w2[((size_t)n*32 + d)*C_DIM + c];
        #pragma unroll
        for (int r = 0; r < 8; r++) {
          const float xv2 = xs[r][n*32 + d];
          m[r][0] += xv2*w.x; m[r][1] += xv2*w.y;
          m[r][2] += xv2*w.z; m[r][3] += xv2*w.w;
        }
      }
      #pragma unroll
      for (int r = 0; r < 8; r++)
        pack4(&outs[n][(size_t)(t0+r)*C_DIM + c],
              xc[r].x + dx[r].x*m[r][0], xc[r].y + dx[r].y*m[r][1],
              xc[r].z + dx[r].z*m[r][2], xc[r].w + dx[r].w*m[r][3]);
    }
  } else {                             // ---- hm ----
    const int b = bid - T/8;
    const int t = b*4 + (tid >> 6);
    const int u = tid & 63;
    const int n = u >> 4, h = u & 15;
    float s = 0.f;
    #pragma unroll 8
    for (int d = 0; d < 32; d++)
      s += ha[(size_t)t*128 + n*32 + d] * hw2[(size_t)(n*32 + d)*16 + h];
    hm[((size_t)n*T + t)*16 + h] = s * (1.f/16.f);
  }
}

// ---------------- 32x64 GEMM body (dist-1 double buffer) ----------------
__device__ __forceinline__ void gemm_body(
    const ushort_t* __restrict__ A, const ushort_t* __restrict__ Bt,
    float* __restrict__ Cm, int b)
{
  const int bn = (b & 15) * 64;
  const int bm = (b >> 4) * 32;
  const int lane = threadIdx.x;
  const int l15 = lane & 15, g = lane >> 4;
  f32x4 acc[2][4];
  #pragma unroll
  for (int i = 0; i < 2; i++)
    #pragma unroll
    for (int j = 0; j < 4; j++) acc[i][j] = (f32x4){0.f,0.f,0.f,0.f};
  bf16x8 a0[2], b0[4], a1[2], b1[4];
  #define LGA(dst, kk) { \
    _Pragma("unroll") \
    for (int i = 0; i < 2; i++) \
      dst[i] = *(const bf16x8*)&A[(size_t)(bm + i*16 + l15)*C_DIM + (kk) + g*8]; }
  #define LGB(dst, kk) { \
    _Pragma("unroll") \
    for (int j = 0; j < 4; j++) \
      dst[j] = *(const bf16x8*)&Bt[(size_t)(bn + j*16 + l15)*C_DIM + (kk) + g*8]; }
  LGA(a0, 0); LGB(b0, 0);
  for (int k0 = 0; k0 < C_DIM; k0 += 64) {
    LGA(a1, k0+32); LGB(b1, k0+32);
    #pragma unroll
    for (int i = 0; i < 2; i++)
      #pragma unroll
      for (int j = 0; j < 4; j++) acc[i][j] = MFMA16(a0[i], b0[j], acc[i][j]);
    if (k0 + 64 < C_DIM) { LGA(a0, k0+64); LGB(b0, k0+64); }
    #pragma unroll
    for (int i = 0; i < 2; i++)
      #pragma unroll
      for (int j = 0; j < 4; j++) acc[i][j] = MFMA16(a1[i], b1[j], acc[i][j]);
  }
  #undef LGA
  #undef LGB
  #pragma unroll
  for (int i = 0; i < 2; i++)
    #pragma unroll
    for (int j = 0; j < 4; j++)
      #pragma unroll
      for (int r = 0; r < 4; r++)
        Cm[(size_t)(bm + i*16 + g*4 + r)*C_DIM + bn + j*16 + l15] = acc[i][j][r];
}

// ---------------- K4: fused 3-way QKV GEMM ----------------
__global__ __launch_bounds__(64) void qkv_gemm(
    const ushort_t* __restrict__ xqb, const ushort_t* __restrict__ xkb,
    const ushort_t* __restrict__ xvb,
    const ushort_t* __restrict__ wtr, const ushort_t* __restrict__ wtk,
    const ushort_t* __restrict__ wtv,
    float* __restrict__ oq, float* __restrict__ ok, float* __restrict__ ov)
{
  const int bid = blockIdx.x;
  const int z = bid >> 10, b = bid & 1023;
  const ushort_t* A  = (z == 0) ? xqb : (z == 1) ? xkb : xvb;
  const ushort_t* Bt = (z == 0) ? wtr : (z == 1) ? wtk : wtv;
  float* Cm          = (z == 0) ? oq  : (z == 1) ? ok  : ov;
  gemm_body(A, Bt, Cm, b);
}

// ---------------- K12: single GEMM (final projection) ----------------
__global__ __launch_bounds__(64) void gemm_bf16(
    const ushort_t* __restrict__ A, const ushort_t* __restrict__ Bt,
    float* __restrict__ Cm)
{
  gemm_body(A, Bt, Cm, blockIdx.x);
}

// ---------------- K5: fused 3-way LayerNorm -> bf16 ----------------
__global__ __launch_bounds__(256) void ln3_rows(
    const float* __restrict__ iq, const float* __restrict__ ik,
    const float* __restrict__ iv,
    ushort_t* __restrict__ oq, ushort_t* __restrict__ ok,
    ushort_t* __restrict__ ov,
    const float* __restrict__ gq, const float* __restrict__ bq,
    const float* __restrict__ gk, const float* __restrict__ bk,
    const float* __restrict__ gv, const float* __restrict__ bv2, int T)
{
  __shared__ float red[4];
  const int bid = blockIdx.x;
  const int z = bid / T, t = bid - z*T;
  const float* in = (z == 0) ? iq : (z == 1) ? ik : iv;
  ushort_t* outp  = (z == 0) ? oq : (z == 1) ? ok : ov;
  const float* g  = (z == 0) ? gq : (z == 1) ? gk : gv;
  const float* b  = (z == 0) ? bq : (z == 1) ? bk : bv2;
  const float scale = (z == 0) ? 0.125f : 1.0f;
  const int tid = threadIdx.x;
  const int c = tid*4;
  const float4 v = *(const float4*)&in[(size_t)t*C_DIM + c];
  float s = v.x+v.y+v.z+v.w;
  #pragma unroll
  for (int off = 32; off > 0; off >>= 1) s += __shfl_down(s, off, 64);
  if ((tid & 63) == 0) red[tid >> 6] = s;
  __syncthreads();
  const float mean = (red[0]+red[1]+red[2]+red[3]) * (1.0f/C_DIM);
  __syncthreads();
  const float d0 = v.x-mean, d1 = v.y-mean, d2 = v.z-mean, d3 = v.w-mean;
  float q = d0*d0 + d1*d1 + d2*d2 + d3*d3;
  #pragma unroll
  for (int off = 32; off > 0; off >>= 1) q += __shfl_down(q, off, 64);
  if ((tid & 63) == 0) red[tid >> 6] = q;
  __syncthreads();
  const float var = (red[0]+red[1]+red[2]+red[3]) * (1.0f/C_DIM);
  const float rstd = rsqrtf(var + 1e-5f);
  const float4 gv4 = *(const float4*)&g[c];
  const float4 bv4 = *(const float4*)&b[c];
  pack4(outp + (size_t)t*C_DIM + c,
        (d0*rstd*gv4.x + bv4.x)*scale, (d1*rstd*gv4.y + bv4.y)*scale,
        (d2*rstd*gv4.z + bv4.z)*scale, (d3*rstd*gv4.w + bv4.w)*scale);
}

// ---------------- K6: vtrans + qek_prep ----------------
__global__ __launch_bounds__(256) void vtrans_qek(
    const ushort_t* __restrict__ vbf, ushort_t* __restrict__ Vt,
    const ushort_t* __restrict__ qbf, const ushort_t* __restrict__ kbf,
    const float* __restrict__ hmb, ushort_t* __restrict__ Qe,
    ushort_t* __restrict__ Ke, float* __restrict__ spo_g, int T)
{
  __shared__ ushort_t tile[32][36];
  const int bid = blockIdx.x;
  const int tid = threadIdx.x;
  const int NV = (T/32) * (C_DIM/32);   // 2048
  if (bid < NV) {                      // ---- vtrans ----
    const int t0 = (bid & 63) * 32, c0 = (bid >> 6) * 32;
    const int r = tid >> 3, c4 = (tid & 7) * 4;
    const uint2 raw = *(const uint2*)&vbf[(size_t)(t0+r)*C_DIM + c0 + c4];
    tile[r][c4+0] = (ushort_t)(raw.x & 0xffffu);
    tile[r][c4+1] = (ushort_t)(raw.x >> 16);
    tile[r][c4+2] = (ushort_t)(raw.y & 0xffffu);
    tile[r][c4+3] = (ushort_t)(raw.y >> 16);
    __syncthreads();
    uint2 w;
    w.x = (unsigned)tile[c4+0][r] | ((unsigned)tile[c4+1][r] << 16);
    w.y = (unsigned)tile[c4+2][r] | ((unsigned)tile[c4+3][r] << 16);
    *(uint2*)&Vt[(size_t)(c0+r)*T + t0 + c4] = w;
  } else {                             // ---- qek_prep ----
    const int t = bid - NV;
    const int c4 = tid * 4;
    const int h = tid >> 4;
    float sp = 0.f, so = 0.f;
    #pragma unroll
    for (int q4 = 0; q4 < 4; q4++) {
      const float4 v = *(const float4*)&hmb[((size_t)1*T + t)*16 + q4*4];
      sp += v.x + v.y + v.z + v.w;
      const float4 o = *(const float4*)&hmb[((size_t)3*T + t)*16 + q4*4];
      so += o.x + o.y + o.z + o.w;
    }
    if (tid == 0) spo_g[t] = so;
    const float preq = hmb[((size_t)0*T + t)*16 + h];
    const float prek = hmb[((size_t)1*T + t)*16 + h];
    const uint2 qr = *(const uint2*)&qbf[(size_t)t*C_DIM + c4];
    const uint2 kr = *(const uint2*)&kbf[(size_t)t*C_DIM + c4];
    float qv[4], kv[4];
    qv[0] = bf2f((ushort_t)(qr.x & 0xffffu)); qv[1] = bf2f((ushort_t)(qr.x >> 16));
    qv[2] = bf2f((ushort_t)(qr.y & 0xffffu)); qv[3] = bf2f((ushort_t)(qr.y >> 16));
    kv[0] = bf2f((ushort_t)(kr.x & 0xffffu)); kv[1] = bf2f((ushort_t)(kr.x >> 16));
    kv[2] = bf2f((ushort_t)(kr.y & 0xffffu)); kv[3] = bf2f((ushort_t)(kr.y >> 16));
    const size_t rb = (size_t)t * 2048;
    pack4(&Qe[rb + c4], qv[0]*preq, qv[1]*preq, qv[2]*preq, qv[3]*preq);
    *(uint2*)&Qe[rb + 1024 + c4] = qr;
    const float osp = 1.f + sp;
    pack4(&Ke[rb + c4], kv[0]*osp, kv[1]*osp, kv[2]*osp, kv[3]*osp);
    pack4(&Ke[rb + 1024 + c4], kv[0]*prek, kv[1]*prek, kv[2]*prek, kv[3]*prek);
  }
}

// ---------------- K7: E GEMM (32x64 causal tiles, K=2048) ----------------
__global__ __launch_bounds__(64) void e_gemm(
    const ushort_t* __restrict__ Qe, const ushort_t* __restrict__ Ke,
    float* __restrict__ E, int T)
{
  const int bm = blockIdx.y * 32;
  const int bn = blockIdx.x * 64;
  if (bn > bm + 31) return;
  const int lane = threadIdx.x;
  const int l15 = lane & 15, g = lane >> 4;
  const int KD = 2048;
  f32x4 acc[2][4];
  #pragma unroll
  for (int i = 0; i < 2; i++)
    #pragma unroll
    for (int j = 0; j < 4; j++) acc[i][j] = (f32x4){0.f,0.f,0.f,0.f};
  bf16x8 a0[2], b0[4], a1[2], b1[4];
  #define LEA(dst, kk) { \
    _Pragma("unroll") \
    for (int i = 0; i < 2; i++) \
      dst[i] = *(const bf16x8*)&Qe[(size_t)(bm + i*16 + l15)*KD + (kk) + g*8]; }
  #define LEB(dst, kk) { \
    _Pragma("unroll") \
    for (int j = 0; j < 4; j++) \
      dst[j] = *(const bf16x8*)&Ke[(size_t)(bn + j*16 + l15)*KD + (kk) + g*8]; }
  LEA(a0, 0); LEB(b0, 0);
  for (int k0 = 0; k0 < KD; k0 += 64) {
    LEA(a1, k0+32); LEB(b1, k0+32);
    #pragma unroll
    for (int i = 0; i < 2; i++)
      #pragma unroll
      for (int j = 0; j < 4; j++) acc[i][j] = MFMA16(a0[i], b0[j], acc[i][j]);
    if (k0 + 64 < KD) { LEA(a0, k0+64); LEB(b0, k0+64); }
    #pragma unroll
    for (int i = 0; i < 2; i++)
      #pragma unroll
      for (int j = 0; j < 4; j++) acc[i][j] = MFMA16(a1[i], b1[j], acc[i][j]);
  }
  #undef LEA
  #undef LEB
  #pragma unroll
  for (int i = 0; i < 2; i++)
    #pragma unroll
    for (int j = 0; j < 4; j++)
      #pragma unroll
      for (int r = 0; r < 4; r++)
        E[(size_t)(bm + i*16 + g*4 + r)*T + bn + j*16 + l15] = acc[i][j][r];
}

// ---------------- K8: pass 1 = scores + fixed-M l + y3 dump ----------------
__global__ __launch_bounds__(512) void attn_stats(
    const ushort_t* __restrict__ qbf, const ushort_t* __restrict__ kbf,
    const float* __restrict__ E, float* __restrict__ part_l,
    ushort_t* __restrict__ y3d, int T)
{
  const int tbi = (int)blockIdx.y;
  const int tb = (T/TQ) - 1 - tbi;
  const int sc = (tbi & 1) ? (7 - (int)blockIdx.x) : (int)blockIdx.x;
  const int t0 = tb * TQ;
  const int sbeg = sc * SCH;
  if (sbeg >= t0 + TQ) return;
  const int send = (sbeg + SCH < t0 + TQ) ? (sbeg + SCH) : (t0 + TQ);
  const int offT = y3_off(tbi);

  const int tid = threadIdx.x;
  const int w = tid >> 6, lane = tid & 63, l15 = lane & 15, g = lane >> 4;
  const int hh[2] = {w, w + 8};
  bf16x8 qf[2][2];
  float slope[2];
  #pragma unroll
  for (int hd = 0; hd < 2; hd++) {
    #pragma unroll
    for (int kc = 0; kc < 2; kc++)
      qf[hd][kc] = *(const bf16x8*)
          &qbf[(size_t)(t0 + l15)*C_DIM + hh[hd]*64 + kc*32 + g*8];
    slope[hd] = exp2f(-0.5f * (float)(hh[hd] + 1));
  }
  float lrun[2] = {0.f, 0.f};

  bf16x8 kf[2][2][2];
  float4 ef[2];
  #define LOADK(sbase) { \
    _Pragma("unroll") \
    for (int hd = 0; hd < 2; hd++) \
      _Pragma("unroll") \
      for (int sh = 0; sh < 2; sh++) \
        _Pragma("unroll") \
        for (int kc = 0; kc < 2; kc++) \
          kf[hd][sh][kc] = *(const bf16x8*)&kbf[ \
              (size_t)((sbase) + sh*16 + l15)*C_DIM + hh[hd]*64 + kc*32 + g*8]; }
  #define LOADE(sbase) { \
    _Pragma("unroll") \
    for (int sh = 0; sh < 2; sh++) \
      ef[sh] = *(const float4*)&E[(size_t)(t0 + l15)*T + (sbase) + sh*16 + g*4]; }
  LOADK(sbeg); LOADE(sbeg);

  for (int s1 = sbeg; s1 < send; s1 += 32) {
    f32x4 acc[2][2];
    #pragma unroll
    for (int hd = 0; hd < 2; hd++)
      #pragma unroll
      for (int sh = 0; sh < 2; sh++) acc[hd][sh] = (f32x4){0.f,0.f,0.f,0.f};
    #pragma unroll
    for (int hd = 0; hd < 2; hd++)
      #pragma unroll
      for (int sh = 0; sh < 2; sh++)
        #pragma unroll
        for (int kc = 0; kc < 2; kc++)
          acc[hd][sh] = MFMA16(kf[hd][sh][kc], qf[hd][kc], acc[hd][sh]);
    float efc[2][4];
    #pragma unroll
    for (int sh = 0; sh < 2; sh++) *(float4*)efc[sh] = ef[sh];
    {
      const int snx = (s1 + 32 < send) ? s1 + 32 : s1;
      LOADK(snx); LOADE(snx);
    }
    ushort_t* slot = y3d + ((size_t)(offT + (s1 >> 5))*512 + tid)*16;
    #pragma unroll
    for (int hd = 0; hd < 2; hd++) {
      const int t = t0 + l15;
      #pragma unroll
      for (int sh = 0; sh < 2; sh++) {
        float y3v[4];
        #pragma unroll
        for (int r = 0; r < 4; r++) {
          const int s = s1 + sh*16 + g*4 + r;
          y3v[r] = acc[hd][sh][r] + efc[sh][r] - slope[hd]*(float)(t - s);
          lrun[hd] += (s <= t) ? __expf(y3v[r] - FIXED_M) : 0.f;
        }
        __half2 h0 = __floats2half2_rn(y3v[0], y3v[1]);
        __half2 h1 = __floats2half2_rn(y3v[2], y3v[3]);
        uint2 pk;
        pk.x = *(unsigned*)&h0;
        pk.y = *(unsigned*)&h1;
        *(uint2*)(slot + (hd*2 + sh)*4) = pk;
      }
    }
  }
  #undef LOADK
  #undef LOADE
  #pragma unroll
  for (int hd = 0; hd < 2; hd++) {
    float L = lrun[hd];
    L += __shfl_xor(L, 16, 64);
    L += __shfl_xor(L, 32, 64);
    if (g == 0)
      part_l[(size_t)(sc*HEADS + hh[hd])*T + t0 + l15] = L;
  }
}

// ---------------- K10: pass 2 = apply from y3 (top-of-loop mem issue) ------
__global__ __launch_bounds__(512) void attn_apply(
    const ushort_t* __restrict__ y3d, const ushort_t* __restrict__ Vt,
    const float* __restrict__ hmb, const float* __restrict__ spo_g,
    const float* __restrict__ part_l, float* __restrict__ P, int T)
{
  __shared__ ushort_t ybuf[HEADS*TQ*PADS];   // 20.5 KB
  __shared__ float ep[TQ*EPS];               // 2.3 KB

  const int tbi = (int)blockIdx.y;
  const int tb = (T/TQ) - 1 - tbi;
  const int sc = (tbi & 1) ? (7 - (int)blockIdx.x) : (int)blockIdx.x;
  const int t0 = tb * TQ;
  const int sbeg = sc * SCH;
  if (sbeg >= t0 + TQ) return;
  const int send = (sbeg + SCH < t0 + TQ) ? (sbeg + SCH) : (t0 + TQ);
  const int prow0 = T*sc - 128*sc*(sc-1) - SCH*sc;
  const int offT = y3_off(tbi);

  const int tid = threadIdx.x;
  const int w = tid >> 6, lane = tid & 63, l15 = lane & 15, g = lane >> 4;
  const int hh[2] = {w, w + 8};
  float li[2];
  const int nsc = (t0 >> 8) + 1;
  #pragma unroll
  for (int hd = 0; hd < 2; hd++) {
    float l = 0.f;
    for (int s2 = 0; s2 < nsc; s2++)
      l += part_l[(size_t)(s2*HEADS + hh[hd])*T + t0 + l15];
    li[hd] = 1.f / l;
  }
  f32x4 oacc[2][4];
  #pragma unroll
  for (int hd = 0; hd < 2; hd++)
    #pragma unroll
    for (int vf = 0; vf < 4; vf++) oacc[hd][vf] = (f32x4){0.f,0.f,0.f,0.f};

  // prefetch first y3 block into registers
  uint2 pk[2][2];
  {
    const ushort_t* slot = y3d + ((size_t)(offT + (sbeg >> 5))*512 + tid)*16;
    #pragma unroll
    for (int hd = 0; hd < 2; hd++)
      #pragma unroll
      for (int sh = 0; sh < 2; sh++)
        pk[hd][sh] = *(const uint2*)(slot + (hd*2 + sh)*4);
  }

  for (int s1 = sbeg; s1 < send; s1 += 32) {
    // ---- issue ALL independent memory at the top of the iteration ----
    bf16x8 vv[2][4];
    #pragma unroll
    for (int hd = 0; hd < 2; hd++)
      #pragma unroll
      for (int vf = 0; vf < 4; vf++)
        vv[hd][vf] = *(const bf16x8*)
            &Vt[(size_t)(hh[hd]*64 + vf*16 + l15)*T + s1 + g*8];
    uint2 pknext[2][2];
    if (s1 + 32 < send) {
      const ushort_t* slot =
          y3d + ((size_t)(offT + ((s1 + 32) >> 5))*512 + tid)*16;
      #pragma unroll
      for (int hd = 0; hd < 2; hd++)
        #pragma unroll
        for (int sh = 0; sh < 2; sh++)
          pknext[hd][sh] = *(const uint2*)(slot + (hd*2 + sh)*4);
    }
    // ---- p = exp(y3 - M) * li  (from prefetched pk) ----
    f32x4 acc[2][2];
    #pragma unroll
    for (int hd = 0; hd < 2; hd++) {
      const int t = t0 + l15;
      #pragma unroll
      for (int sh = 0; sh < 2; sh++) {
        const float2 f0 = __half22float2(*(const __half2*)&pk[hd][sh].x);
        const float2 f1 = __half22float2(*(const __half2*)&pk[hd][sh].y);
        const float y3v[4] = {f0.x, f0.y, f1.x, f1.y};
        #pragma unroll
        for (int r = 0; r < 4; r++) {
          const int s = s1 + sh*16 + g*4 + r;
          float p = 0.f;
          if (s <= t) p = __expf(y3v[r] - FIXED_M) * li[hd];
          acc[hd][sh][r] = p;
        }
        pack4(&ybuf[(size_t)(hh[hd]*TQ + l15)*PADS + sh*16 + g*4],
              acc[hd][sh][0], acc[hd][sh][1], acc[hd][sh][2], acc[hd][sh][3]);
      }
    }
    __syncthreads();                     // bar1: p ready
    // e_post: ALL 512 threads, one (tc,scell) cell each
    {
      const int tc = tid >> 5, scell = tid & 31;
      const int s0g = s1 + scell;
      float a = 0.f, b = 0.f;
      #pragma unroll
      for (int h4 = 0; h4 < 4; h4++) {
        const float4 hq4 = *(const float4*)&hmb[((size_t)2*T + t0 + tc)*16 + h4*4];
        const float4 hk4 = *(const float4*)&hmb[((size_t)3*T + s0g)*16 + h4*4];
        const float hqa[4] = {hq4.x, hq4.y, hq4.z, hq4.w};
        const float hka[4] = {hk4.x, hk4.y, hk4.z, hk4.w};
        #pragma unroll
        for (int j = 0; j < 4; j++) {
          const float y = bf2f(ybuf[((h4*4 + j)*TQ + tc)*PADS + scell]);
          a += y * hqa[j];
          b += y * hka[j];
        }
      }
      ep[tc*EPS + scell] = a*(1.f + spo_g[s0g]) + b;
    }
    __syncthreads();                     // bar2: ep ready; ybuf reads done
    // p2 = p + e_post, pack, PV  (vv already resident)
    {
      float epv[2][4];
      #pragma unroll
      for (int sh = 0; sh < 2; sh++)
        *(float4*)epv[sh] = *(const float4*)&ep[l15*EPS + sh*16 + g*4];
      #pragma unroll
      for (int hd = 0; hd < 2; hd++)
        #pragma unroll
        for (int sh = 0; sh < 2; sh++)
          pack4(&ybuf[(size_t)(hh[hd]*TQ + l15)*PADS + sh*16 + g*4],
                acc[hd][sh][0] + epv[sh][0], acc[hd][sh][1] + epv[sh][1],
                acc[hd][sh][2] + epv[sh][2], acc[hd][sh][3] + epv[sh][3]);
    }
    #pragma unroll
    for (int hd = 0; hd < 2; hd++) {
      const bf16x8 pa = *(const bf16x8*)
          &ybuf[(size_t)(hh[hd]*TQ + l15)*PADS + g*8];   // wave-local rows
      #pragma unroll
      for (int vf = 0; vf < 4; vf++)
        oacc[hd][vf] = MFMA16(pa, vv[hd][vf], oacc[hd][vf]);
    }
    #pragma unroll
    for (int hd = 0; hd < 2; hd++)
      #pragma unroll
      for (int sh = 0; sh < 2; sh++)
        pk[hd][sh] = pknext[hd][sh];
  }
  #pragma unroll
  for (int hd = 0; hd < 2; hd++)
    #pragma unroll
    for (int vf = 0; vf < 4; vf++)
      #pragma unroll
      for (int r = 0; r < 4; r++)
        P[(size_t)(prow0 + t0 + g*4 + r)*C_DIM + hh[hd]*64 + vf*16 + l15]
            = oacc[hd][vf][r];
}

// ---------------- K11: reduce partials + LayerNorm -> bf16 -----------------
__global__ __launch_bounds__(256) void reduce_ln(
    const float* __restrict__ P, ushort_t* __restrict__ outp,
    const float* __restrict__ g, const float* __restrict__ b, int T)
{
  __shared__ float red[4];
  const int t = blockIdx.x;
  const int tid = threadIdx.x;
  const int c = tid*4;
  const int nsc = (t >> 8) + 1;
  float4 v = make_float4(0.f, 0.f, 0.f, 0.f);
  int off = 0;
  for (int sc = 0; sc < nsc; sc++) {
    const int row = off + t - sc*SCH;
    const float4 pv = *(const float4*)&P[(size_t)row*C_DIM + c];
    v.x += pv.x; v.y += pv.y; v.z += pv.z; v.w += pv.w;
    off += T - SCH*sc;
  }
  float s = v.x+v.y+v.z+v.w;
  #pragma unroll
  for (int o = 32; o > 0; o >>= 1) s += __shfl_down(s, o, 64);
  if ((tid & 63) == 0) red[tid >> 6] = s;
  __syncthreads();
  const float mean = (red[0]+red[1]+red[2]+red[3]) * (1.0f/C_DIM);
  __syncthreads();
  const float d0 = v.x-mean, d1 = v.y-mean, d2 = v.z-mean, d3 = v.w-mean;
  float q = d0*d0 + d1*d1 + d2*d2 + d3*d3;
  #pragma unroll
  for (int o = 32; o > 0; o >>= 1) q += __shfl_down(q, o, 64);
  if ((tid & 63) == 0) red[tid >> 6] = q;
  __syncthreads();
  const float var = (red[0]+red[1]+red[2]+red[3]) * (1.0f/C_DIM);
  const float rstd = rsqrtf(var + 1e-5f);
  const float4 gv = *(const float4*)&g[c];
  const float4 bv = *(const float4*)&b[c];
  pack4(outp + (size_t)t*C_DIM + c,
        d0*rstd*gv.x + bv.x, d1*rstd*gv.y + bv.y,
        d2*rstd*gv.z + bv.z, d3*rstd*gv.w + bv.w);
}

// ---------------- launcher ----------------
extern "C" void kernel_launch(void* const* d_in, const int* in_sizes, int n_in,
                              void* d_out, int out_size, void* d_ws, size_t ws_size,
                              hipStream_t stream)
{
  const float* x      = (const float*)d_in[0];
  const float* shift  = (const float*)d_in[1];
  const float* maa_x  = (const float*)d_in[2];
  const float* maa_r  = (const float*)d_in[3];
  const float* maa_k  = (const float*)d_in[4];
  const float* maa_v  = (const float*)d_in[5];
  const float* w1     = (const float*)d_in[6];
  const float* w2     = (const float*)d_in[7];
  const float* hw1    = (const float*)d_in[8];
  const float* hw2    = (const float*)d_in[9];
  const float* w_r    = (const float*)d_in[10];
  const float* w_k    = (const float*)d_in[11];
  const float* w_v    = (const float*)d_in[12];
  const float* w_o    = (const float*)d_in[13];
  const float* ln_r_g = (const float*)d_in[14];
  const float* ln_r_b = (const float*)d_in[15];
  const float* ln_k_g = (const float*)d_in[16];
  const float* ln_k_b = (const float*)d_in[17];
  const float* ln_v_g = (const float*)d_in[18];
  const float* ln_v_b = (const float*)d_in[19];
  const float* ln_x_g = (const float*)d_in[20];
  const float* ln_x_b = (const float*)d_in[21];

  const int T = in_sizes[0] / C_DIM;            // 2048
  const size_t MM = (size_t)T * C_DIM;          // 2M f32 elems
  const size_t HF = MM / 2;

  float* ws = (float*)d_ws;
  float*    P      = ws;
  float*    dxprev = ws;
  ushort_t* zbf    = (ushort_t*)(ws + MM);
  ushort_t* xbf    = (ushort_t*)(ws + MM + HF);
  float*    gtmpQ  = ws;
  float*    gtmpK  = ws + MM;
  float*    gtmpV  = ws + 2*MM;
  ushort_t* xqb    = (ushort_t*)(ws + 3*MM);
  ushort_t* xkb    = (ushort_t*)(ws + 3*MM + HF);
  ushort_t* xvb    = (ushort_t*)(ws + 4*MM);
  ushort_t* Qe     = (ushort_t*)ws;
  ushort_t* Ke     = (ushort_t*)(ws + MM);
  float* base2 = ws + 4*MM + HF;                  // = 4.5*MM
  ushort_t* qbf = (ushort_t*)(base2 + 0*HF);
  ushort_t* kbf = (ushort_t*)(base2 + 1*HF);
  ushort_t* vbf = (ushort_t*)(base2 + 2*HF);
  ushort_t* Vt  = (ushort_t*)(base2 + 3*HF);
  ushort_t* wtr = (ushort_t*)(base2 + 4*HF);
  ushort_t* wtk = wtr + (size_t)C_DIM*C_DIM;
  ushort_t* wtv = wtk + (size_t)C_DIM*C_DIM;
  ushort_t* wto = wtv + (size_t)C_DIM*C_DIM;
  float* after_w = base2 + 4*HF + (size_t)2*C_DIM*C_DIM;
  ushort_t* wlt = (ushort_t*)after_w;             // 224*1024 bf16
  float* xxx    = after_w + 131072;               // T*96
  float* ha     = xxx + (size_t)T*96;             // T*128
  float* hmb    = ha + (size_t)T*128;             // 4*T*16
  float* part_l = hmb + (size_t)4*T*16;           // 8*HEADS*T
  float* spo_g  = part_l + (size_t)8*HEADS*T;     // T
  float* abf_f  = spo_g + (size_t)T;
  ushort_t* abf = (ushort_t*)abf_f;               // HF
  float* Ebuf   = abf_f + HF;                     // T*T f32
  ushort_t* y3d = (ushort_t*)(Ebuf + (size_t)T*T);  // ~68 MB fp16

  prep_all<<<T + 224 + 4096, 256, 0, stream>>>(
      x, shift, maa_x, dxprev, zbf, xbf, w1, hw1, wlt,
      w_r, w_k, w_v, w_o, wtr, wtk, wtv, wto, T);
  lora_gemm<<<dim3(T/32, 7), 64, 0, stream>>>(zbf, xbf, wlt, xxx, ha);
  mix_hm<<<T/8 + T/4, 256, 0, stream>>>(x, dxprev, xxx, ha,
      maa_r, maa_k, maa_v, w2, hw2, xqb, xkb, xvb, hmb, T);
  qkv_gemm<<<3*1024, 64, 0, stream>>>(xqb, xkb, xvb, wtr, wtk, wtv,
                                      gtmpQ, gtmpK, gtmpV);
  ln3_rows<<<3*T, 256, 0, stream>>>(gtmpQ, gtmpK, gtmpV, qbf, kbf, vbf,
      ln_r_g, ln_r_b, ln_k_g, ln_k_b, ln_v_g, ln_v_b, T);
  vtrans_qek<<<(T/32)*(C_DIM/32) + T, 256, 0, stream>>>(
      vbf, Vt, qbf, kbf, hmb, Qe, Ke, spo_g, T);
  e_gemm<<<dim3(T/64, T/32), 64, 0, stream>>>(Qe, Ke, Ebuf, T);
  attn_stats<<<dim3(8, T/TQ), 512, 0, stream>>>(
      qbf, kbf, Ebuf, part_l, y3d, T);
  attn_apply<<<dim3(8, T/TQ), 512, 0, stream>>>(
      y3d, Vt, hmb, spo_g, part_l, P, T);
  reduce_ln<<<T, 256, 0, stream>>>(P, abf, ln_x_g, ln_x_b, T);
  gemm_bf16<<<(T/32)*(C_DIM/64), 64, 0, stream>>>(abf, wto, (float*)d_out);
}

// Round 20
// 464.486 us; speedup vs baseline: 1.1287x; 1.0140x over previous
//
#include <hip/hip_runtime.h>
#include <hip/hip_fp16.h>
#include <cstdint>
#include <cstddef>

// RWKV_Tmix_headmixer — round 20: R19 champion + distance-2 y3 prefetch in
// attn_apply (pk/pk1 resident, s+64 issued at loop top: ~2 iterations of
// compute cover the ~900cy HBM y3 latency instead of 1). All else identical.
// B=1, T=2048, C=1024, H=16, K=64.

#define C_DIM 1024
#define HEADS 16
#define TQ 16
#define SCH 256
#define PADS 40
#define EPS 36
#define FIXED_M 40.0f

typedef unsigned short ushort_t;
typedef __attribute__((ext_vector_type(8))) short bf16x8;
typedef __attribute__((ext_vector_type(4))) float f32x4;

#define MFMA16(a, b, c) __builtin_amdgcn_mfma_f32_16x16x32_bf16(a, b, c, 0, 0, 0)

__device__ __forceinline__ unsigned int f2bf_u(float f) {
  unsigned int u = __float_as_uint(f);
  return (u + 0x7fffu + ((u >> 16) & 1u)) >> 16;   // RNE
}
__device__ __forceinline__ float bf2f(ushort_t u) {
  return __uint_as_float(((unsigned int)u) << 16);
}
__device__ __forceinline__ void pack4(ushort_t* dst, float x0, float x1,
                                      float x2, float x3) {
  uint2 v;
  v.x = f2bf_u(x0) | (f2bf_u(x1) << 16);
  v.y = f2bf_u(x2) | (f2bf_u(x3) << 16);
  *(uint2*)dst = v;
}
// packed y3 tile-slot offset: ntiles(tbi) = ceil((t0+16)/32), t0=(127-tbi)*16
__device__ __forceinline__ int y3_off(int tbi) {
  const int m = tbi >> 1;
  const int S = m*(m-1) + ((tbi & 1) ? m : 0);
  return 64*tbi - S;
}

// ---------------- K1: prep_all = prep + wlora_prep + wprep(x4) -------------
__global__ __launch_bounds__(256) void prep_all(
    const float* __restrict__ x, const float* __restrict__ shift,
    const float* __restrict__ maa_x,
    float* __restrict__ dxprev, ushort_t* __restrict__ zbf,
    ushort_t* __restrict__ xbf,
    const float* __restrict__ w1, const float* __restrict__ hw1,
    ushort_t* __restrict__ wlt,
    const float* __restrict__ w_r, const float* __restrict__ w_k,
    const float* __restrict__ w_v, const float* __restrict__ w_o,
    ushort_t* __restrict__ wtr, ushort_t* __restrict__ wtk,
    ushort_t* __restrict__ wtv, ushort_t* __restrict__ wto, int T)
{
  __shared__ float tile[32][33];
  const int bid = blockIdx.x;
  const int tid = threadIdx.x;
  if (bid < T) {                       // ---- prep ----
    const int t = bid;
    const int c = tid * 4;
    const size_t base = (size_t)t * C_DIM + c;
    const float4 xc = *(const float4*)&x[base];
    const float4 xp = (t == 0) ? *(const float4*)&shift[c]
                               : *(const float4*)&x[base - C_DIM];
    const float4 mx = *(const float4*)&maa_x[c];
    float4 d;
    d.x = xp.x - xc.x; d.y = xp.y - xc.y; d.z = xp.z - xc.z; d.w = xp.w - xc.w;
    *(float4*)&dxprev[base] = d;
    pack4(&zbf[base], xc.x + d.x*mx.x, xc.y + d.y*mx.y,
          xc.z + d.z*mx.z, xc.w + d.w*mx.w);
    pack4(&xbf[base], xc.x, xc.y, xc.z, xc.w);
  } else if (bid < T + 224) {          // ---- wlora_prep ----
    const int b = bid - T;
    const int k0 = (b & 31) * 32, j0 = (b >> 5) * 32;
    const int r = tid >> 3, c4 = (tid & 7) * 4;
    const float* W = (j0 < 96) ? w1 : hw1;
    const int stride = (j0 < 96) ? 96 : 128;
    const int jo = (j0 < 96) ? j0 : j0 - 96;
    const float4 v = *(const float4*)&W[(size_t)(k0+r)*stride + jo + c4];
    tile[r][c4+0] = v.x; tile[r][c4+1] = v.y;
    tile[r][c4+2] = v.z; tile[r][c4+3] = v.w;
    __syncthreads();
    pack4(&wlt[(size_t)(j0+r)*C_DIM + k0 + c4],
          tile[c4+0][r], tile[c4+1][r], tile[c4+2][r], tile[c4+3][r]);
  } else {                             // ---- wprep x4 ----
    const int b = bid - T - 224;
    const int z = b >> 10, rr = b & 1023;
    const int k0 = (rr & 31) * 32, n0 = (rr >> 5) * 32;
    const float* W; ushort_t* O;
    if (z == 0)      { W = w_r; O = wtr; }
    else if (z == 1) { W = w_k; O = wtk; }
    else if (z == 2) { W = w_v; O = wtv; }
    else             { W = w_o; O = wto; }
    const int r = tid >> 3, c4 = (tid & 7) * 4;
    const float4 v = *(const float4*)&W[(size_t)(k0+r)*C_DIM + n0 + c4];
    tile[r][c4+0] = v.x; tile[r][c4+1] = v.y;
    tile[r][c4+2] = v.z; tile[r][c4+3] = v.w;
    __syncthreads();
    pack4(&O[(size_t)(n0+r)*C_DIM + k0 + c4],
          tile[c4+0][r], tile[c4+1][r], tile[c4+2][r], tile[c4+3][r]);
  }
}

// ---------------- K2: lora GEMM with tanh epilogue ----------------
__global__ __launch_bounds__(64) void lora_gemm(
    const ushort_t* __restrict__ zbf, const ushort_t* __restrict__ xbf,
    const ushort_t* __restrict__ wlt, float* __restrict__ xxx,
    float* __restrict__ ha)
{
  const int nt = blockIdx.y;
  const int bm = blockIdx.x * 32;
  const ushort_t* A = (nt < 3) ? zbf : xbf;
  const int wrow = nt * 32;
  const int lane = threadIdx.x;
  const int l15 = lane & 15, g = lane >> 4;
  f32x4 acc[2][2];
  #pragma unroll
  for (int i = 0; i < 2; i++)
    #pragma unroll
    for (int j = 0; j < 2; j++) acc[i][j] = (f32x4){0.f,0.f,0.f,0.f};
  bf16x8 a0[2], b0[2], a1[2], b1[2];
  #define LLA(aa, bb, kk) { \
    _Pragma("unroll") \
    for (int i = 0; i < 2; i++) { \
      aa[i] = *(const bf16x8*)&A[(size_t)(bm + i*16 + l15)*C_DIM + (kk) + g*8]; \
      bb[i] = *(const bf16x8*)&wlt[(size_t)(wrow + i*16 + l15)*C_DIM + (kk) + g*8]; \
    } }
  LLA(a0, b0, 0);
  for (int k0 = 0; k0 < C_DIM; k0 += 64) {
    LLA(a1, b1, k0+32);
    #pragma unroll
    for (int i = 0; i < 2; i++)
      #pragma unroll
      for (int j = 0; j < 2; j++) acc[i][j] = MFMA16(a0[i], b0[j], acc[i][j]);
    if (k0 + 64 < C_DIM) LLA(a0, b0, k0+64);
    #pragma unroll
    for (int i = 0; i < 2; i++)
      #pragma unroll
      for (int j = 0; j < 2; j++) acc[i][j] = MFMA16(a1[i], b1[j], acc[i][j]);
  }
  #undef LLA
  #pragma unroll
  for (int i = 0; i < 2; i++)
    #pragma unroll
    for (int j = 0; j < 2; j++)
      #pragma unroll
      for (int r = 0; r < 4; r++) {
        const int t = bm + i*16 + g*4 + r;
        const int col = wrow + j*16 + l15;
        const float val = tanhf(acc[i][j][r]);
        if (nt < 3) xxx[(size_t)t*96 + col] = val;
        else        ha[(size_t)t*128 + col - 96] = val;
      }
}

// ---------------- K3: mix + hm ----------------
__global__ __launch_bounds__(256) void mix_hm(
    const float* __restrict__ x, const float* __restrict__ dxp,
    const float* __restrict__ xxx, const float* __restrict__ ha,
    const float* __restrict__ maa_r, const float* __restrict__ maa_k,
    const float* __restrict__ maa_v, const float* __restrict__ w2,
    const float* __restrict__ hw2,
    ushort_t* __restrict__ xq, ushort_t* __restrict__ xk,
    ushort_t* __restrict__ xv, float* __restrict__ hm, int T)
{
  __shared__ float xs[8][96];
  const int bid = blockIdx.x;
  const int tid = threadIdx.x;
  if (bid < T/8) {                     // ---- mix ----
    const int t0 = bid * 8;
    #pragma unroll
    for (int i = 0; i < 3; i++) {
      const int u = tid + i*256;
      if (u < 768) {
        const int r = u / 96, cc = u % 96;
        xs[r][cc] = xxx[(size_t)(t0+r)*96 + cc];
      }
    }
    __syncthreads();
    const int c = tid * 4;
    float4 xc[8], dx[8];
    #pragma unroll
    for (int r = 0; r < 8; r++) {
      xc[r] = *(const float4*)&x[(size_t)(t0+r)*C_DIM + c];
      dx[r] = *(const float4*)&dxp[(size_t)(t0+r)*C_DIM + c];
    }
    const float* maas[3] = {maa_r, maa_k, maa_v};
    ushort_t* outs[3] = {xq, xk, xv};
    #pragma unroll
    for (int n = 0; n < 3; n++) {
      const float4 mv = *(const float4*)&maas[n][c];
      float m[8][4];
      #pragma unroll
      for (int r = 0; r < 8; r++) {
        m[r][0] = mv.x; m[r][1] = mv.y; m[r][2] = mv.z; m[r][3] = mv.w;
      }
      #pragma unroll 8
      for (int d = 0; d < 32; d++) {
        const float4 w = *(const float4*)&w2[((size_t)n*32 + d)*C_DIM + c];
        #pragma unroll
        for (int r = 0; r < 8; r++) {
          const float xv2 = xs[r][n*32 + d];
          m[r][0] += xv2*w.x; m[r][1] += xv2*w.y;
          m[r][2] += xv2*w.z; m[r][3] += xv2*w.w;
        }
      }
      #pragma unroll
      for (int r = 0; r < 8; r++)
        pack4(&outs[n][(size_t)(t0+r)*C_DIM + c],
              xc[r].x + dx[r].x*m[r][0], xc[r].y + dx[r].y*m[r][1],
              xc[r].z + dx[r].z*m[r][2], xc[r].w + dx[r].w*m[r][3]);
    }
  } else {                             // ---- hm ----
    const int b = bid - T/8;
    const int t = b*4 + (tid >> 6);
    const int u = tid & 63;
    const int n = u >> 4, h = u & 15;
    float s = 0.f;
    #pragma unroll 8
    for (int d = 0; d < 32; d++)
      s += ha[(size_t)t*128 + n*32 + d] * hw2[(size_t)(n*32 + d)*16 + h];
    hm[((size_t)n*T + t)*16 + h] = s * (1.f/16.f);
  }
}

// ---------------- 32x64 GEMM body (dist-1 double buffer) ----------------
__device__ __forceinline__ void gemm_body(
    const ushort_t* __restrict__ A, const ushort_t* __restrict__ Bt,
    float* __restrict__ Cm, int b)
{
  const int bn = (b & 15) * 64;
  const int bm = (b >> 4) * 32;
  const int lane = threadIdx.x;
  const int l15 = lane & 15, g = lane >> 4;
  f32x4 acc[2][4];
  #pragma unroll
  for (int i = 0; i < 2; i++)
    #pragma unroll
    for (int j = 0; j < 4; j++) acc[i][j] = (f32x4){0.f,0.f,0.f,0.f};
  bf16x8 a0[2], b0[4], a1[2], b1[4];
  #define LGA(dst, kk) { \
    _Pragma("unroll") \
    for (int i = 0; i < 2; i++) \
      dst[i] = *(const bf16x8*)&A[(size_t)(bm + i*16 + l15)*C_DIM + (kk) + g*8]; }
  #define LGB(dst, kk) { \
    _Pragma("unroll") \
    for (int j = 0; j < 4; j++) \
      dst[j] = *(const bf16x8*)&Bt[(size_t)(bn + j*16 + l15)*C_DIM + (kk) + g*8]; }
  LGA(a0, 0); LGB(b0, 0);
  for (int k0 = 0; k0 < C_DIM; k0 += 64) {
    LGA(a1, k0+32); LGB(b1, k0+32);
    #pragma unroll
    for (int i = 0; i < 2; i++)
      #pragma unroll
      for (int j = 0; j < 4; j++) acc[i][j] = MFMA16(a0[i], b0[j], acc[i][j]);
    if (k0 + 64 < C_DIM) { LGA(a0, k0+64); LGB(b0, k0+64); }
    #pragma unroll
    for (int i = 0; i < 2; i++)
      #pragma unroll
      for (int j = 0; j < 4; j++) acc[i][j] = MFMA16(a1[i], b1[j], acc[i][j]);
  }
  #undef LGA
  #undef LGB
  #pragma unroll
  for (int i = 0; i < 2; i++)
    #pragma unroll
    for (int j = 0; j < 4; j++)
      #pragma unroll
      for (int r = 0; r < 4; r++)
        Cm[(size_t)(bm + i*16 + g*4 + r)*C_DIM + bn + j*16 + l15] = acc[i][j][r];
}

// ---------------- K4: fused 3-way QKV GEMM ----------------
__global__ __launch_bounds__(64) void qkv_gemm(
    const ushort_t* __restrict__ xqb, const ushort_t* __restrict__ xkb,
    const ushort_t* __restrict__ xvb,
    const ushort_t* __restrict__ wtr, const ushort_t* __restrict__ wtk,
    const ushort_t* __restrict__ wtv,
    float* __restrict__ oq, float* __restrict__ ok, float* __restrict__ ov)
{
  const int bid = blockIdx.x;
  const int z = bid >> 10, b = bid & 1023;
  const ushort_t* A  = (z == 0) ? xqb : (z == 1) ? xkb : xvb;
  const ushort_t* Bt = (z == 0) ? wtr : (z == 1) ? wtk : wtv;
  float* Cm          = (z == 0) ? oq  : (z == 1) ? ok  : ov;
  gemm_body(A, Bt, Cm, b);
}

// ---------------- K12: single GEMM (final projection) ----------------
__global__ __launch_bounds__(64) void gemm_bf16(
    const ushort_t* __restrict__ A, const ushort_t* __restrict__ Bt,
    float* __restrict__ Cm)
{
  gemm_body(A, Bt, Cm, blockIdx.x);
}

// ---------------- K5: fused 3-way LayerNorm -> bf16 ----------------
__global__ __launch_bounds__(256) void ln3_rows(
    const float* __restrict__ iq, const float* __restrict__ ik,
    const float* __restrict__ iv,
    ushort_t* __restrict__ oq, ushort_t* __restrict__ ok,
    ushort_t* __restrict__ ov,
    const float* __restrict__ gq, const float* __restrict__ bq,
    const float* __restrict__ gk, const float* __restrict__ bk,
    const float* __restrict__ gv, const float* __restrict__ bv2, int T)
{
  __shared__ float red[4];
  const int bid = blockIdx.x;
  const int z = bid / T, t = bid - z*T;
  const float* in = (z == 0) ? iq : (z == 1) ? ik : iv;
  ushort_t* outp  = (z == 0) ? oq : (z == 1) ? ok : ov;
  const float* g  = (z == 0) ? gq : (z == 1) ? gk : gv;
  const float* b  = (z == 0) ? bq : (z == 1) ? bk : bv2;
  const float scale = (z == 0) ? 0.125f : 1.0f;
  const int tid = threadIdx.x;
  const int c = tid*4;
  const float4 v = *(const float4*)&in[(size_t)t*C_DIM + c];
  float s = v.x+v.y+v.z+v.w;
  #pragma unroll
  for (int off = 32; off > 0; off >>= 1) s += __shfl_down(s, off, 64);
  if ((tid & 63) == 0) red[tid >> 6] = s;
  __syncthreads();
  const float mean = (red[0]+red[1]+red[2]+red[3]) * (1.0f/C_DIM);
  __syncthreads();
  const float d0 = v.x-mean, d1 = v.y-mean, d2 = v.z-mean, d3 = v.w-mean;
  float q = d0*d0 + d1*d1 + d2*d2 + d3*d3;
  #pragma unroll
  for (int off = 32; off > 0; off >>= 1) q += __shfl_down(q, off, 64);
  if ((tid & 63) == 0) red[tid >> 6] = q;
  __syncthreads();
  const float var = (red[0]+red[1]+red[2]+red[3]) * (1.0f/C_DIM);
  const float rstd = rsqrtf(var + 1e-5f);
  const float4 gv4 = *(const float4*)&g[c];
  const float4 bv4 = *(const float4*)&b[c];
  pack4(outp + (size_t)t*C_DIM + c,
        (d0*rstd*gv4.x + bv4.x)*scale, (d1*rstd*gv4.y + bv4.y)*scale,
        (d2*rstd*gv4.z + bv4.z)*scale, (d3*rstd*gv4.w + bv4.w)*scale);
}

// ---------------- K6: vtrans + qek_prep ----------------
__global__ __launch_bounds__(256) void vtrans_qek(
    const ushort_t* __restrict__ vbf, ushort_t* __restrict__ Vt,
    const ushort_t* __restrict__ qbf, const ushort_t* __restrict__ kbf,
    const float* __restrict__ hmb, ushort_t* __restrict__ Qe,
    ushort_t* __restrict__ Ke, float* __restrict__ spo_g, int T)
{
  __shared__ ushort_t tile[32][36];
  const int bid = blockIdx.x;
  const int tid = threadIdx.x;
  const int NV = (T/32) * (C_DIM/32);   // 2048
  if (bid < NV) {                      // ---- vtrans ----
    const int t0 = (bid & 63) * 32, c0 = (bid >> 6) * 32;
    const int r = tid >> 3, c4 = (tid & 7) * 4;
    const uint2 raw = *(const uint2*)&vbf[(size_t)(t0+r)*C_DIM + c0 + c4];
    tile[r][c4+0] = (ushort_t)(raw.x & 0xffffu);
    tile[r][c4+1] = (ushort_t)(raw.x >> 16);
    tile[r][c4+2] = (ushort_t)(raw.y & 0xffffu);
    tile[r][c4+3] = (ushort_t)(raw.y >> 16);
    __syncthreads();
    uint2 w;
    w.x = (unsigned)tile[c4+0][r] | ((unsigned)tile[c4+1][r] << 16);
    w.y = (unsigned)tile[c4+2][r] | ((unsigned)tile[c4+3][r] << 16);
    *(uint2*)&Vt[(size_t)(c0+r)*T + t0 + c4] = w;
  } else {                             // ---- qek_prep ----
    const int t = bid - NV;
    const int c4 = tid * 4;
    const int h = tid >> 4;
    float sp = 0.f, so = 0.f;
    #pragma unroll
    for (int q4 = 0; q4 < 4; q4++) {
      const float4 v = *(const float4*)&hmb[((size_t)1*T + t)*16 + q4*4];
      sp += v.x + v.y + v.z + v.w;
      const float4 o = *(const float4*)&hmb[((size_t)3*T + t)*16 + q4*4];
      so += o.x + o.y + o.z + o.w;
    }
    if (tid == 0) spo_g[t] = so;
    const float preq = hmb[((size_t)0*T + t)*16 + h];
    const float prek = hmb[((size_t)1*T + t)*16 + h];
    const uint2 qr = *(const uint2*)&qbf[(size_t)t*C_DIM + c4];
    const uint2 kr = *(const uint2*)&kbf[(size_t)t*C_DIM + c4];
    float qv[4], kv[4];
    qv[0] = bf2f((ushort_t)(qr.x & 0xffffu)); qv[1] = bf2f((ushort_t)(qr.x >> 16));
    qv[2] = bf2f((ushort_t)(qr.y & 0xffffu)); qv[3] = bf2f((ushort_t)(qr.y >> 16));
    kv[0] = bf2f((ushort_t)(kr.x & 0xffffu)); kv[1] = bf2f((ushort_t)(kr.x >> 16));
    kv[2] = bf2f((ushort_t)(kr.y & 0xffffu)); kv[3] = bf2f((ushort_t)(kr.y >> 16));
    const size_t rb = (size_t)t * 2048;
    pack4(&Qe[rb + c4], qv[0]*preq, qv[1]*preq, qv[2]*preq, qv[3]*preq);
    *(uint2*)&Qe[rb + 1024 + c4] = qr;
    const float osp = 1.f + sp;
    pack4(&Ke[rb + c4], kv[0]*osp, kv[1]*osp, kv[2]*osp, kv[3]*osp);
    pack4(&Ke[rb + 1024 + c4], kv[0]*prek, kv[1]*prek, kv[2]*prek, kv[3]*prek);
  }
}

// ---------------- K7: E GEMM (32x64 causal tiles, K=2048) ----------------
__global__ __launch_bounds__(64) void e_gemm(
    const ushort_t* __restrict__ Qe, const ushort_t* __restrict__ Ke,
    float* __restrict__ E, int T)
{
  const int bm = blockIdx.y * 32;
  const int bn = blockIdx.x * 64;
  if (bn > bm + 31) return;
  const int lane = threadIdx.x;
  const int l15 = lane & 15, g = lane >> 4;
  const int KD = 2048;
  f32x4 acc[2][4];
  #pragma unroll
  for (int i = 0; i < 2; i++)
    #pragma unroll
    for (int j = 0; j < 4; j++) acc[i][j] = (f32x4){0.f,0.f,0.f,0.f};
  bf16x8 a0[2], b0[4], a1[2], b1[4];
  #define LEA(dst, kk) { \
    _Pragma("unroll") \
    for (int i = 0; i < 2; i++) \
      dst[i] = *(const bf16x8*)&Qe[(size_t)(bm + i*16 + l15)*KD + (kk) + g*8]; }
  #define LEB(dst, kk) { \
    _Pragma("unroll") \
    for (int j = 0; j < 4; j++) \
      dst[j] = *(const bf16x8*)&Ke[(size_t)(bn + j*16 + l15)*KD + (kk) + g*8]; }
  LEA(a0, 0); LEB(b0, 0);
  for (int k0 = 0; k0 < KD; k0 += 64) {
    LEA(a1, k0+32); LEB(b1, k0+32);
    #pragma unroll
    for (int i = 0; i < 2; i++)
      #pragma unroll
      for (int j = 0; j < 4; j++) acc[i][j] = MFMA16(a0[i], b0[j], acc[i][j]);
    if (k0 + 64 < KD) { LEA(a0, k0+64); LEB(b0, k0+64); }
    #pragma unroll
    for (int i = 0; i < 2; i++)
      #pragma unroll
      for (int j = 0; j < 4; j++) acc[i][j] = MFMA16(a1[i], b1[j], acc[i][j]);
  }
  #undef LEA
  #undef LEB
  #pragma unroll
  for (int i = 0; i < 2; i++)
    #pragma unroll
    for (int j = 0; j < 4; j++)
      #pragma unroll
      for (int r = 0; r < 4; r++)
        E[(size_t)(bm + i*16 + g*4 + r)*T + bn + j*16 + l15] = acc[i][j][r];
}

// ---------------- K8: pass 1 = scores + fixed-M l + y3 dump ----------------
__global__ __launch_bounds__(512) void attn_stats(
    const ushort_t* __restrict__ qbf, const ushort_t* __restrict__ kbf,
    const float* __restrict__ E, float* __restrict__ part_l,
    ushort_t* __restrict__ y3d, int T)
{
  const int tbi = (int)blockIdx.y;
  const int tb = (T/TQ) - 1 - tbi;
  const int sc = (tbi & 1) ? (7 - (int)blockIdx.x) : (int)blockIdx.x;
  const int t0 = tb * TQ;
  const int sbeg = sc * SCH;
  if (sbeg >= t0 + TQ) return;
  const int send = (sbeg + SCH < t0 + TQ) ? (sbeg + SCH) : (t0 + TQ);
  const int offT = y3_off(tbi);

  const int tid = threadIdx.x;
  const int w = tid >> 6, lane = tid & 63, l15 = lane & 15, g = lane >> 4;
  const int hh[2] = {w, w + 8};
  bf16x8 qf[2][2];
  float slope[2];
  #pragma unroll
  for (int hd = 0; hd < 2; hd++) {
    #pragma unroll
    for (int kc = 0; kc < 2; kc++)
      qf[hd][kc] = *(const bf16x8*)
          &qbf[(size_t)(t0 + l15)*C_DIM + hh[hd]*64 + kc*32 + g*8];
    slope[hd] = exp2f(-0.5f * (float)(hh[hd] + 1));
  }
  float lrun[2] = {0.f, 0.f};

  bf16x8 kf[2][2][2];
  float4 ef[2];
  #define LOADK(sbase) { \
    _Pragma("unroll") \
    for (int hd = 0; hd < 2; hd++) \
      _Pragma("unroll") \
      for (int sh = 0; sh < 2; sh++) \
        _Pragma("unroll") \
        for (int kc = 0; kc < 2; kc++) \
          kf[hd][sh][kc] = *(const bf16x8*)&kbf[ \
              (size_t)((sbase) + sh*16 + l15)*C_DIM + hh[hd]*64 + kc*32 + g*8]; }
  #define LOADE(sbase) { \
    _Pragma("unroll") \
    for (int sh = 0; sh < 2; sh++) \
      ef[sh] = *(const float4*)&E[(size_t)(t0 + l15)*T + (sbase) + sh*16 + g*4]; }
  LOADK(sbeg); LOADE(sbeg);

  for (int s1 = sbeg; s1 < send; s1 += 32) {
    f32x4 acc[2][2];
    #pragma unroll
    for (int hd = 0; hd < 2; hd++)
      #pragma unroll
      for (int sh = 0; sh < 2; sh++) acc[hd][sh] = (f32x4){0.f,0.f,0.f,0.f};
    #pragma unroll
    for (int hd = 0; hd < 2; hd++)
      #pragma unroll
      for (int sh = 0; sh < 2; sh++)
        #pragma unroll
        for (int kc = 0; kc < 2; kc++)
          acc[hd][sh] = MFMA16(kf[hd][sh][kc], qf[hd][kc], acc[hd][sh]);
    float efc[2][4];
    #pragma unroll
    for (int sh = 0; sh < 2; sh++) *(float4*)efc[sh] = ef[sh];
    {
      const int snx = (s1 + 32 < send) ? s1 + 32 : s1;
      LOADK(snx); LOADE(snx);
    }
    ushort_t* slot = y3d + ((size_t)(offT + (s1 >> 5))*512 + tid)*16;
    #pragma unroll
    for (int hd = 0; hd < 2; hd++) {
      const int t = t0 + l15;
      #pragma unroll
      for (int sh = 0; sh < 2; sh++) {
        float y3v[4];
        #pragma unroll
        for (int r = 0; r < 4; r++) {
          const int s = s1 + sh*16 + g*4 + r;
          y3v[r] = acc[hd][sh][r] + efc[sh][r] - slope[hd]*(float)(t - s);
          lrun[hd] += (s <= t) ? __expf(y3v[r] - FIXED_M) : 0.f;
        }
        __half2 h0 = __floats2half2_rn(y3v[0], y3v[1]);
        __half2 h1 = __floats2half2_rn(y3v[2], y3v[3]);
        uint2 pk;
        pk.x = *(unsigned*)&h0;
        pk.y = *(unsigned*)&h1;
        *(uint2*)(slot + (hd*2 + sh)*4) = pk;
      }
    }
  }
  #undef LOADK
  #undef LOADE
  #pragma unroll
  for (int hd = 0; hd < 2; hd++) {
    float L = lrun[hd];
    L += __shfl_xor(L, 16, 64);
    L += __shfl_xor(L, 32, 64);
    if (g == 0)
      part_l[(size_t)(sc*HEADS + hh[hd])*T + t0 + l15] = L;
  }
}

// ---------------- K10: pass 2 = apply from y3 (dist-2 y3 prefetch) ---------
__global__ __launch_bounds__(512) void attn_apply(
    const ushort_t* __restrict__ y3d, const ushort_t* __restrict__ Vt,
    const float* __restrict__ hmb, const float* __restrict__ spo_g,
    const float* __restrict__ part_l, float* __restrict__ P, int T)
{
  __shared__ ushort_t ybuf[HEADS*TQ*PADS];   // 20.5 KB
  __shared__ float ep[TQ*EPS];               // 2.3 KB

  const int tbi = (int)blockIdx.y;
  const int tb = (T/TQ) - 1 - tbi;
  const int sc = (tbi & 1) ? (7 - (int)blockIdx.x) : (int)blockIdx.x;
  const int t0 = tb * TQ;
  const int sbeg = sc * SCH;
  if (sbeg >= t0 + TQ) return;
  const int send = (sbeg + SCH < t0 + TQ) ? (sbeg + SCH) : (t0 + TQ);
  const int prow0 = T*sc - 128*sc*(sc-1) - SCH*sc;
  const int offT = y3_off(tbi);

  const int tid = threadIdx.x;
  const int w = tid >> 6, lane = tid & 63, l15 = lane & 15, g = lane >> 4;
  const int hh[2] = {w, w + 8};
  float li[2];
  const int nsc = (t0 >> 8) + 1;
  #pragma unroll
  for (int hd = 0; hd < 2; hd++) {
    float l = 0.f;
    for (int s2 = 0; s2 < nsc; s2++)
      l += part_l[(size_t)(s2*HEADS + hh[hd])*T + t0 + l15];
    li[hd] = 1.f / l;
  }
  f32x4 oacc[2][4];
  #pragma unroll
  for (int hd = 0; hd < 2; hd++)
    #pragma unroll
    for (int vf = 0; vf < 4; vf++) oacc[hd][vf] = (f32x4){0.f,0.f,0.f,0.f};

  // distance-2 y3 prefetch: pk = tile s1, pk1 = tile s1+32
  uint2 pk[2][2], pk1[2][2];
  {
    const ushort_t* slot = y3d + ((size_t)(offT + (sbeg >> 5))*512 + tid)*16;
    #pragma unroll
    for (int hd = 0; hd < 2; hd++)
      #pragma unroll
      for (int sh = 0; sh < 2; sh++)
        pk[hd][sh] = *(const uint2*)(slot + (hd*2 + sh)*4);
  }
  if (sbeg + 32 < send) {
    const ushort_t* slot =
        y3d + ((size_t)(offT + ((sbeg + 32) >> 5))*512 + tid)*16;
    #pragma unroll
    for (int hd = 0; hd < 2; hd++)
      #pragma unroll
      for (int sh = 0; sh < 2; sh++)
        pk1[hd][sh] = *(const uint2*)(slot + (hd*2 + sh)*4);
  }

  for (int s1 = sbeg; s1 < send; s1 += 32) {
    // ---- issue ALL independent memory at the top of the iteration ----
    bf16x8 vv[2][4];
    #pragma unroll
    for (int hd = 0; hd < 2; hd++)
      #pragma unroll
      for (int vf = 0; vf < 4; vf++)
        vv[hd][vf] = *(const bf16x8*)
            &Vt[(size_t)(hh[hd]*64 + vf*16 + l15)*T + s1 + g*8];
    uint2 pk2[2][2];
    if (s1 + 64 < send) {              // prefetch tile s1+64 (2 ahead)
      const ushort_t* slot =
          y3d + ((size_t)(offT + ((s1 + 64) >> 5))*512 + tid)*16;
      #pragma unroll
      for (int hd = 0; hd < 2; hd++)
        #pragma unroll
        for (int sh = 0; sh < 2; sh++)
          pk2[hd][sh] = *(const uint2*)(slot + (hd*2 + sh)*4);
    }
    // ---- p = exp(y3 - M) * li  (from pk, loaded 2 iterations ago) ----
    f32x4 acc[2][2];
    #pragma unroll
    for (int hd = 0; hd < 2; hd++) {
      const int t = t0 + l15;
      #pragma unroll
      for (int sh = 0; sh < 2; sh++) {
        const float2 f0 = __half22float2(*(const __half2*)&pk[hd][sh].x);
        const float2 f1 = __half22float2(*(const __half2*)&pk[hd][sh].y);
        const float y3v[4] = {f0.x, f0.y, f1.x, f1.y};
        #pragma unroll
        for (int r = 0; r < 4; r++) {
          const int s = s1 + sh*16 + g*4 + r;
          float p = 0.f;
          if (s <= t) p = __expf(y3v[r] - FIXED_M) * li[hd];
          acc[hd][sh][r] = p;
        }
        pack4(&ybuf[(size_t)(hh[hd]*TQ + l15)*PADS + sh*16 + g*4],
              acc[hd][sh][0], acc[hd][sh][1], acc[hd][sh][2], acc[hd][sh][3]);
      }
    }
    __syncthreads();                     // bar1: p ready
    // e_post: ALL 512 threads, one (tc,scell) cell each
    {
      const int tc = tid >> 5, scell = tid & 31;
      const int s0g = s1 + scell;
      float a = 0.f, b = 0.f;
      #pragma unroll
      for (int h4 = 0; h4 < 4; h4++) {
        const float4 hq4 = *(const float4*)&hmb[((size_t)2*T + t0 + tc)*16 + h4*4];
        const float4 hk4 = *(const float4*)&hmb[((size_t)3*T + s0g)*16 + h4*4];
        const float hqa[4] = {hq4.x, hq4.y, hq4.z, hq4.w};
        const float hka[4] = {hk4.x, hk4.y, hk4.z, hk4.w};
        #pragma unroll
        for (int j = 0; j < 4; j++) {
          const float y = bf2f(ybuf[((h4*4 + j)*TQ + tc)*PADS + scell]);
          a += y * hqa[j];
          b += y * hka[j];
        }
      }
      ep[tc*EPS + scell] = a*(1.f + spo_g[s0g]) + b;
    }
    __syncthreads();                     // bar2: ep ready; ybuf reads done
    // p2 = p + e_post, pack, PV  (vv already resident)
    {
      float epv[2][4];
      #pragma unroll
      for (int sh = 0; sh < 2; sh++)
        *(float4*)epv[sh] = *(const float4*)&ep[l15*EPS + sh*16 + g*4];
      #pragma unroll
      for (int hd = 0; hd < 2; hd++)
        #pragma unroll
        for (int sh = 0; sh < 2; sh++)
          pack4(&ybuf[(size_t)(hh[hd]*TQ + l15)*PADS + sh*16 + g*4],
                acc[hd][sh][0] + epv[sh][0], acc[hd][sh][1] + epv[sh][1],
                acc[hd][sh][2] + epv[sh][2], acc[hd][sh][3] + epv[sh][3]);
    }
    #pragma unroll
    for (int hd = 0; hd < 2; hd++) {
      const bf16x8 pa = *(const bf16x8*)
          &ybuf[(size_t)(hh[hd]*TQ + l15)*PADS + g*8];   // wave-local rows
      #pragma unroll
      for (int vf = 0; vf < 4; vf++)
        oacc[hd][vf] = MFMA16(pa, vv[hd][vf], oacc[hd][vf]);
    }
    // rotate prefetch registers: pk <- pk1 <- pk2
    #pragma unroll
    for (int hd = 0; hd < 2; hd++)
      #pragma unroll
      for (int sh = 0; sh < 2; sh++) {
        pk[hd][sh] = pk1[hd][sh];
        pk1[hd][sh] = pk2[hd][sh];
      }
  }
  #pragma unroll
  for (int hd = 0; hd < 2; hd++)
    #pragma unroll
    for (int vf = 0; vf < 4; vf++)
      #pragma unroll
      for (int r = 0; r < 4; r++)
        P[(size_t)(prow0 + t0 + g*4 + r)*C_DIM + hh[hd]*64 + vf*16 + l15]
            = oacc[hd][vf][r];
}

// ---------------- K11: reduce partials + LayerNorm -> bf16 -----------------
__global__ __launch_bounds__(256) void reduce_ln(
    const float* __restrict__ P, ushort_t* __restrict__ outp,
    const float* __restrict__ g, const float* __restrict__ b, int T)
{
  __shared__ float red[4];
  const int t = blockIdx.x;
  const int tid = threadIdx.x;
  const int c = tid*4;
  const int nsc = (t >> 8) + 1;
  float4 v = make_float4(0.f, 0.f, 0.f, 0.f);
  int off = 0;
  for (int sc = 0; sc < nsc; sc++) {
    const int row = off + t - sc*SCH;
    const float4 pv = *(const float4*)&P[(size_t)row*C_DIM + c];
    v.x += pv.x; v.y += pv.y; v.z += pv.z; v.w += pv.w;
    off += T - SCH*sc;
  }
  float s = v.x+v.y+v.z+v.w;
  #pragma unroll
  for (int o = 32; o > 0; o >>= 1) s += __shfl_down(s, o, 64);
  if ((tid & 63) == 0) red[tid >> 6] = s;
  __syncthreads();
  const float mean = (red[0]+red[1]+red[2]+red[3]) * (1.0f/C_DIM);
  __syncthreads();
  const float d0 = v.x-mean, d1 = v.y-mean, d2 = v.z-mean, d3 = v.w-mean;
  float q = d0*d0 + d1*d1 + d2*d2 + d3*d3;
  #pragma unroll
  for (int o = 32; o > 0; o >>= 1) q += __shfl_down(q, o, 64);
  if ((tid & 63) == 0) red[tid >> 6] = q;
  __syncthreads();
  const float var = (red[0]+red[1]+red[2]+red[3]) * (1.0f/C_DIM);
  const float rstd = rsqrtf(var + 1e-5f);
  const float4 gv = *(const float4*)&g[c];
  const float4 bv = *(const float4*)&b[c];
  pack4(outp + (size_t)t*C_DIM + c,
        d0*rstd*gv.x + bv.x, d1*rstd*gv.y + bv.y,
        d2*rstd*gv.z + bv.z, d3*rstd*gv.w + bv.w);
}

// ---------------- launcher ----------------
extern "C" void kernel_launch(void* const* d_in, const int* in_sizes, int n_in,
                              void* d_out, int out_size, void* d_ws, size_t ws_size,
                              hipStream_t stream)
{
  const float* x      = (const float*)d_in[0];
  const float* shift  = (const float*)d_in[1];
  const float* maa_x  = (const float*)d_in[2];
  const float* maa_r  = (const float*)d_in[3];
  const float* maa_k  = (const float*)d_in[4];
  const float* maa_v  = (const float*)d_in[5];
  const float* w1     = (const float*)d_in[6];
  const float* w2     = (const float*)d_in[7];
  const float* hw1    = (const float*)d_in[8];
  const float* hw2    = (const float*)d_in[9];
  const float* w_r    = (const float*)d_in[10];
  const float* w_k    = (const float*)d_in[11];
  const float* w_v    = (const float*)d_in[12];
  const float* w_o    = (const float*)d_in[13];
  const float* ln_r_g = (const float*)d_in[14];
  const float* ln_r_b = (const float*)d_in[15];
  const float* ln_k_g = (const float*)d_in[16];
  const float* ln_k_b = (const float*)d_in[17];
  const float* ln_v_g = (const float*)d_in[18];
  const float* ln_v_b = (const float*)d_in[19];
  const float* ln_x_g = (const float*)d_in[20];
  const float* ln_x_b = (const float*)d_in[21];

  const int T = in_sizes[0] / C_DIM;            // 2048
  const size_t MM = (size_t)T * C_DIM;          // 2M f32 elems
  const size_t HF = MM / 2;

  float* ws = (float*)d_ws;
  float*    P      = ws;
  float*    dxprev = ws;
  ushort_t* zbf    = (ushort_t*)(ws + MM);
  ushort_t* xbf    = (ushort_t*)(ws + MM + HF);
  float*    gtmpQ  = ws;
  float*    gtmpK  = ws + MM;
  float*    gtmpV  = ws + 2*MM;
  ushort_t* xqb    = (ushort_t*)(ws + 3*MM);
  ushort_t* xkb    = (ushort_t*)(ws + 3*MM + HF);
  ushort_t* xvb    = (ushort_t*)(ws + 4*MM);
  ushort_t* Qe     = (ushort_t*)ws;
  ushort_t* Ke     = (ushort_t*)(ws + MM);
  float* base2 = ws + 4*MM + HF;                  // = 4.5*MM
  ushort_t* qbf = (ushort_t*)(base2 + 0*HF);
  ushort_t* kbf = (ushort_t*)(base2 + 1*HF);
  ushort_t* vbf = (ushort_t*)(base2 + 2*HF);
  ushort_t* Vt  = (ushort_t*)(base2 + 3*HF);
  ushort_t* wtr = (ushort_t*)(base2 + 4*HF);
  ushort_t* wtk = wtr + (size_t)C_DIM*C_DIM;
  ushort_t* wtv = wtk + (size_t)C_DIM*C_DIM;
  ushort_t* wto = wtv + (size_t)C_DIM*C_DIM;
  float* after_w = base2 + 4*HF + (size_t)2*C_DIM*C_DIM;
  ushort_t* wlt = (ushort_t*)after_w;             // 224*1024 bf16
  float* xxx    = after_w + 131072;               // T*96
  float* ha     = xxx + (size_t)T*96;             // T*128
  float* hmb    = ha + (size_t)T*128;             // 4*T*16
  float* part_l = hmb + (size_t)4*T*16;           // 8*HEADS*T
  float* spo_g  = part_l + (size_t)8*HEADS*T;     // T
  float* abf_f  = spo_g + (size_t)T;
  ushort_t* abf = (ushort_t*)abf_f;               // HF
  float* Ebuf   = abf_f + HF;                     // T*T f32
  ushort_t* y3d = (ushort_t*)(Ebuf + (size_t)T*T);  // ~68 MB fp16

  prep_all<<<T + 224 + 4096, 256, 0, stream>>>(
      x, shift, maa_x, dxprev, zbf, xbf, w1, hw1, wlt,
      w_r, w_k, w_v, w_o, wtr, wtk, wtv, wto, T);
  lora_gemm<<<dim3(T/32, 7), 64, 0, stream>>>(zbf, xbf, wlt, xxx, ha);
  mix_hm<<<T/8 + T/4, 256, 0, stream>>>(x, dxprev, xxx, ha,
      maa_r, maa_k, maa_v, w2, hw2, xqb, xkb, xvb, hmb, T);
  qkv_gemm<<<3*1024, 64, 0, stream>>>(xqb, xkb, xvb, wtr, wtk, wtv,
                                      gtmpQ, gtmpK, gtmpV);
  ln3_rows<<<3*T, 256, 0, stream>>>(gtmpQ, gtmpK, gtmpV, qbf, kbf, vbf,
      ln_r_g, ln_r_b, ln_k_g, ln_k_b, ln_v_g, ln_v_b, T);
  vtrans_qek<<<(T/32)*(C_DIM/32) + T, 256, 0, stream>>>(
      vbf, Vt, qbf, kbf, hmb, Qe, Ke, spo_g, T);
  e_gemm<<<dim3(T/64, T/32), 64, 0, stream>>>(Qe, Ke, Ebuf, T);
  attn_stats<<<dim3(8, T/TQ), 512, 0, stream>>>(
      qbf, kbf, Ebuf, part_l, y3d, T);
  attn_apply<<<dim3(8, T/TQ), 512, 0, stream>>>(
      y3d, Vt, hmb, spo_g, part_l, P, T);
  reduce_ln<<<T, 256, 0, stream>>>(P, abf, ln_x_g, ln_x_b, T);
  gemm_bf16<<<(T/32)*(C_DIM/64), 64, 0, stream>>>(abf, wto, (float*)d_out);
}